// Round 8
// baseline (428.721 us; speedup 1.0000x reference)
//
#include <hip/hip_runtime.h>

#define DEVFN __device__ __forceinline__

namespace {
constexpr int B    = 512;
constexpr int D    = 200;
constexpr int RNUM = 200;
constexpr int REL  = 1800;
constexpr int FH   = 58, FW = 18, NP = FH * FW;     // 1044
constexpr int IMH  = 60, IMW = 20, IMN = IMH * IMW; // 1200
constexpr float EPS = 1e-5f;
constexpr float INV_SQRT_D = 0.07071067811865475f;  // 1/sqrt(200)

// workspace layout (float offsets)
constexpr int OFF_X    = 0;                      // B*IMN  conv image (bn0'd)
constexpr int OFF_EM   = OFF_X   + B * IMN;      // B*D
constexpr int OFF_R    = OFF_EM  + B * D;        // B*REL
constexpr int OFF_W    = OFF_R   + B * REL;      // B*REL  bn2(r)
constexpr int OFF_Q    = OFF_W   + B * REL;      // B*D
constexpr int OFF_K    = OFF_Q   + B * D;        // B*D    K TRANSPOSED: kT[d][b]
constexpr int OFF_V    = OFF_K   + B * D;        // B*D    V normal: v[b][d]
constexpr int OFF_ATT  = OFF_V   + B * D;        // B*D
constexpr int OFF_S    = OFF_ATT + B * D;        // B*9
constexpr int OFF_G    = OFF_S   + B * 9;        // B*45
constexpr int OFF_BN0P = OFF_G   + B * 45;       // 96 = 6 slots * 8 chunks * {sum,sq}
constexpr int OFF_BN2M = OFF_BN0P + 96;          // REL
constexpr int OFF_BN2S = OFF_BN2M + REL;         // REL
constexpr int OFF_BN1M = OFF_BN2S + REL;         // RNUM
constexpr int OFF_BN1S = OFF_BN1M + RNUM;        // RNUM
constexpr int OFF_WP   = OFF_BN1S + RNUM;        // NP
constexpr int OFF_BP   = OFF_WP  + NP;           // 1
} // namespace

DEVFN float waveSum(float v) {
#pragma unroll
  for (int o = 32; o; o >>= 1) v += __shfl_down(v, o, 64);
  return v;
}
DEVFN float waveMax(float v) {
#pragma unroll
  for (int o = 32; o; o >>= 1) v = fmaxf(v, __shfl_down(v, o, 64));
  return v;
}
DEVFN float blockSum256(float v, float* sm) {
  int lane = threadIdx.x & 63, w = threadIdx.x >> 6;
  v = waveSum(v);
  if (lane == 0) sm[w] = v;
  __syncthreads();
  if (threadIdx.x == 0) sm[4] = sm[0] + sm[1] + sm[2] + sm[3];
  __syncthreads();
  float t = sm[4];
  __syncthreads();
  return t;
}
DEVFN float blockMax256(float v, float* sm) {
  int lane = threadIdx.x & 63, w = threadIdx.x >> 6;
  v = waveMax(v);
  if (lane == 0) sm[w] = v;
  __syncthreads();
  if (threadIdx.x == 0) sm[4] = fmaxf(fmaxf(sm[0], sm[1]), fmaxf(sm[2], sm[3]));
  __syncthreads();
  float t = sm[4];
  __syncthreads();
  return t;
}
DEVFN float blockSum384(float v, float* sm) {
  int lane = threadIdx.x & 63, w = threadIdx.x >> 6;  // 0..5
  v = waveSum(v);
  if (lane == 0) sm[w] = v;
  __syncthreads();
  if (threadIdx.x == 0) sm[6] = sm[0] + sm[1] + sm[2] + sm[3] + sm[4] + sm[5];
  __syncthreads();
  float t = sm[6];
  __syncthreads();
  return t;
}

// ---- K1: gather 6 entity slots (48 blocks: slot x batch-chunk), bn0 partial moments
__global__ __launch_bounds__(256) void k_gather48(
    const int* i1, const int* i2, const int* i3, const int* i4, const int* i5,
    const int* i6, const float* Ew, float* ws) {
  __shared__ float red[8];
  int blk = blockIdx.x, t = threadIdx.x;
  int s = blk >> 3, ch = blk & 7;
  const int* idx = (s == 0) ? i1 : (s == 1) ? i2 : (s == 2) ? i3
                 : (s == 3) ? i4 : (s == 4) ? i5 : i6;
  float sum = 0.f, sq = 0.f;
  for (int ii = t; ii < 64 * D; ii += 256) {
    int b = ch * 64 + ii / D, d = ii % D;
    float v = Ew[(long long)idx[b] * D + d];
    ws[OFF_X + b * IMN + s * D + d] = v;
    sum += v; sq += v * v;
  }
  float ts = blockSum256(sum, red);
  float tq = blockSum256(sq, red);
  if (t == 0) {
    ws[OFF_BN0P + (s * 8 + ch) * 2]     = ts;
    ws[OFF_BN0P + (s * 8 + ch) * 2 + 1] = tq;
  }
}

// ---- K2: gather relation rows (512 blocks, float4)
__global__ __launch_bounds__(256) void k_gather_r(const int* ridx, const float* Rw,
                                                  float* ws) {
  int b = blockIdx.x, t = threadIdx.x;
  const float4* src = (const float4*)(Rw + (long long)ridx[b] * REL);
  float4* dst = (float4*)(ws + OFF_R + b * REL);
  for (int c = t; c < REL / 4; c += 256) dst[c] = src[c];
}

// ---- K3: bn0 finalize + apply + e_mean (400 blocks cover B*D exactly)
__global__ __launch_bounds__(256) void k_bn0_apply(const float* g0, const float* b0, float* ws) {
  __shared__ float stats[12];
  int blk = blockIdx.x, t = threadIdx.x;
  if (t < 6) {
    float sum = 0.f, sq = 0.f;
#pragma unroll
    for (int ch = 0; ch < 8; ch++) {
      sum += ws[OFF_BN0P + (t * 8 + ch) * 2];
      sq  += ws[OFF_BN0P + (t * 8 + ch) * 2 + 1];
    }
    const float n = (float)(B * D);
    float m = sum / n;
    float var = sq / n - m * m;
    stats[2 * t] = m;
    stats[2 * t + 1] = rsqrtf(var + EPS);
  }
  __syncthreads();
  int i = blk * 256 + t;                  // i < B*D always (400*256 == B*D)
  int b = i / D, d = i - b * D;
  float g = g0[0], bb = b0[0];
  float acc = 0.f;
#pragma unroll
  for (int s = 0; s < 6; s++) {
    float v = ws[OFF_X + b * IMN + s * D + d];
    v = (v - stats[2 * s]) * stats[2 * s + 1] * g + bb;
    ws[OFF_X + b * IMN + s * D + d] = v;
    acc += v;
  }
  ws[OFF_EM + i] = acc * (1.f / 6.f);
}

// ---- K4: per-sample patch moments S[9], G[45] (Gram trick for BN1)
__global__ __launch_bounds__(256) void k_gram(float* ws) {
  __shared__ float img[IMN];
  int b = blockIdx.x, t = threadIdx.x;
  for (int i = t; i < IMN; i += 256) img[i] = ws[OFF_X + b * IMN + i];
  __syncthreads();
  float S[9]; float G[45];
#pragma unroll
  for (int a = 0; a < 9; a++) S[a] = 0.f;
#pragma unroll
  for (int u = 0; u < 45; u++) G[u] = 0.f;
  for (int p = t; p < NP; p += 256) {
    int oy = p / FW, ox = p - oy * FW;
    float tp[9];
#pragma unroll
    for (int kh = 0; kh < 3; kh++)
#pragma unroll
      for (int kw = 0; kw < 3; kw++)
        tp[kh * 3 + kw] = img[(oy + kh) * IMW + ox + kw];
    int u = 0;
#pragma unroll
    for (int a = 0; a < 9; a++) {
      S[a] += tp[a];
#pragma unroll
      for (int c = a; c < 9; c++) { G[u] += tp[a] * tp[c]; u++; }
    }
  }
#pragma unroll
  for (int a = 0; a < 9; a++) S[a] = waveSum(S[a]);
#pragma unroll
  for (int u = 0; u < 45; u++) G[u] = waveSum(G[u]);
  __shared__ float part[4][54];
  int lane = t & 63, w = t >> 6;
  if (lane == 0) {
#pragma unroll
    for (int a = 0; a < 9; a++) part[w][a] = S[a];
#pragma unroll
    for (int u = 0; u < 45; u++) part[w][9 + u] = G[u];
  }
  __syncthreads();
  if (t < 54) {
    float v = part[0][t] + part[1][t] + part[2][t] + part[3][t];
    if (t < 9) ws[OFF_S + b * 9 + t] = v;
    else       ws[OFF_G + b * 45 + (t - 9)] = v;
  }
}

// ---- K5: BN2 per-column stats (8 blocks, covers all 1800 columns)
__global__ __launch_bounds__(256) void k_bn2_stats(float* ws) {
  int c = blockIdx.x * 256 + threadIdx.x;
  if (c >= REL) return;
  const float* r = ws + OFF_R;
  float s = 0.f, q = 0.f;
  for (int b = 0; b < B; b++) { float v = r[b * REL + c]; s += v; q += v * v; }
  float m = s / (float)B;
  float var = q / (float)B - m * m;
  ws[OFF_BN2M + c] = m;
  ws[OFF_BN2S + c] = rsqrtf(var + EPS);
}

// ---- K6: q = e_mean @ Q
__global__ __launch_bounds__(256) void k_q(const float* Qm, float* ws) {
  int i = blockIdx.x * 256 + threadIdx.x;
  if (i >= B * D) return;
  int b = i / D, col = i - b * D;
  const float* em = ws + OFF_EM + b * D;
  float a = 0.f;
  for (int d = 0; d < D; d++) a = fmaf(em[d], Qm[d * D + col], a);
  ws[OFF_Q + i] = a;
}

// ---- K7: k = r@K (stored transposed), v = r@V — round-1 proven pattern:
// 128 blocks x 4 rows, full-REL reduction, PLAIN stores (no atomics — atomics
// were the ~100us pathology in rounds 4-6: memory-side line RMW, 18x write amp).
__global__ __launch_bounds__(256) void k_kv(const float* Km, const float* Vm, float* ws) {
  int bq = blockIdx.x;           // 128 blocks x 4 rows
  int i = threadIdx.x;
  if (i >= D) return;
  const float* r0 = ws + OFF_R + (bq * 4) * REL;
  float ak[4] = {0.f, 0.f, 0.f, 0.f}, av[4] = {0.f, 0.f, 0.f, 0.f};
  for (int c = 0; c < REL; c++) {
    float km = Km[c * D + i], vm = Vm[c * D + i];
#pragma unroll
    for (int u = 0; u < 4; u++) {
      float rv = r0[u * REL + c];
      ak[u] = fmaf(rv, km, ak[u]);
      av[u] = fmaf(rv, vm, av[u]);
    }
  }
#pragma unroll
  for (int u = 0; u < 4; u++) {
    ws[OFF_K + i * B + (bq * 4 + u)] = ak[u];   // kT[d][b] (plain scatter store)
    ws[OFF_V + (bq * 4 + u) * D + i] = av[u];   // v[b][d]  (coalesced)
  }
}

// ---- K8: apply BN2 -> conv weights
__global__ __launch_bounds__(256) void k_bn2_apply(const float* g2, const float* b2, float* ws) {
  int i = blockIdx.x * 256 + threadIdx.x;
  if (i >= B * REL) return;
  int c = i % REL;
  float v = ws[OFF_R + i];
  ws[OFF_W + i] = (v - ws[OFF_BN2M + c]) * ws[OFF_BN2S + c] * g2[c] + b2[c];
}

// ---- K9: attention, 2 queries/block, coalesced kT score loads
__global__ __launch_bounds__(256) void k_attn(float* ws) {
  __shared__ float qs[2][D];
  __shared__ float sc[2][B];
  __shared__ float red[8];
  int blk = blockIdx.x, t = threadIdx.x;
  int b0 = blk * 2;
  for (int i = t; i < 2 * D; i += 256) qs[i / D][i % D] = ws[OFF_Q + b0 * D + i];
  __syncthreads();
  const float* kT = ws + OFF_K;
  float lmax0 = -1e30f, lmax1 = -1e30f;
#pragma unroll
  for (int jj = 0; jj < 2; jj++) {
    int j = t + jj * 256;
    float a0 = 0.f, a1 = 0.f;
    for (int d = 0; d < D; d++) {
      float kv = kT[d * B + j];
      a0 = fmaf(qs[0][d], kv, a0);
      a1 = fmaf(qs[1][d], kv, a1);
    }
    a0 *= INV_SQRT_D; a1 *= INV_SQRT_D;
    sc[0][j] = a0; sc[1][j] = a1;
    lmax0 = fmaxf(lmax0, a0); lmax1 = fmaxf(lmax1, a1);
  }
  float gmax0 = blockMax256(lmax0, red);
  float gmax1 = blockMax256(lmax1, red);
  float lsum0 = 0.f, lsum1 = 0.f;
#pragma unroll
  for (int jj = 0; jj < 2; jj++) {
    int j = t + jj * 256;
    float e0 = __expf(sc[0][j] - gmax0);
    float e1 = __expf(sc[1][j] - gmax1);
    sc[0][j] = e0; sc[1][j] = e1;
    lsum0 += e0; lsum1 += e1;
  }
  float tot0 = blockSum256(lsum0, red);
  float tot1 = blockSum256(lsum1, red);
  float inv0 = 1.f / tot0, inv1 = 1.f / tot1;
  if (t < D) {
    const float* v = ws + OFF_V;
    float a0 = 0.f, a1 = 0.f;
#pragma unroll 4
    for (int j = 0; j < B; j++) {
      float vv = v[j * D + t];
      a0 = fmaf(sc[0][j], vv, a0);
      a1 = fmaf(sc[1][j], vv, a1);
    }
    ws[OFF_ATT + b0 * D + t]       = a0 * inv0;
    ws[OFF_ATT + (b0 + 1) * D + t] = a1 * inv1;
  }
}

// ---- K10: BN1 per-channel stats from (w, S, G)
__global__ __launch_bounds__(256) void k_bn1_stats(float* ws) {
  __shared__ float red[8];
  int j = blockIdx.x, t = threadIdx.x;
  float s = 0.f, q = 0.f;
  for (int b = t; b < B; b += 256) {
    const float* w9 = ws + OFF_W + b * REL + j * 9;
    float wr[9];
#pragma unroll
    for (int k = 0; k < 9; k++) wr[k] = w9[k];
    const float* Sb = ws + OFF_S + b * 9;
    const float* Gb = ws + OFF_G + b * 45;
    float sl = 0.f;
#pragma unroll
    for (int k = 0; k < 9; k++) sl = fmaf(wr[k], Sb[k], sl);
    float ql = 0.f;
    int u = 0;
#pragma unroll
    for (int a = 0; a < 9; a++) {
      ql = fmaf(wr[a] * wr[a], Gb[u], ql); u++;
#pragma unroll
      for (int c = a + 1; c < 9; c++) { ql = fmaf(2.f * wr[a] * wr[c], Gb[u], ql); u++; }
    }
    s += sl; q += ql;
  }
  float ts = blockSum256(s, red);
  float tq = blockSum256(q, red);
  if (t == 0) {
    const float N = (float)B * (float)NP;
    float m = ts / N;
    float var = tq / N - m * m;
    ws[OFF_BN1M + j] = m;
    ws[OFF_BN1S + j] = rsqrtf(var + EPS);
  }
}

// ---- K11: wp = fc6_W^T @ p , bp = fc6_b . p
__global__ __launch_bounds__(256) void k_wp(const float* W, const float* bias,
                                            const float* pv, float* ws) {
  int p = blockIdx.x * 256 + threadIdx.x;
  if (p < NP) {
    float a = 0.f;
    for (int n = 0; n < 100; n++) a = fmaf(W[n * NP + p], pv[n], a);
    ws[OFF_WP + p] = a;
  } else if (p == NP) {
    float a = 0.f;
    for (int n = 0; n < 100; n++) a = fmaf(bias[n], pv[n], a);
    ws[OFF_BP] = a;
  }
}

// ---- K12: final fused conv + BN1 + relu + attention + spatial fc reduce (384 thr)
__global__ __launch_bounds__(384) void k_final(const float* g1, const float* b1,
                                               float* ws, float* out) {
  __shared__ float img[IMN];
  __shared__ float wpl[NP];
  __shared__ float packed[RNUM * 12];   // [w0..w8]*sc, bb, aj, pad
  __shared__ float red[8];
  int b = blockIdx.x, t = threadIdx.x;
  for (int i = t; i < IMN; i += 384) img[i] = ws[OFF_X + b * IMN + i];
  for (int i = t; i < NP; i += 384) wpl[i] = ws[OFF_WP + i];
  if (t < RNUM) {
    int j = t;
    float m = ws[OFF_BN1M + j], is = ws[OFF_BN1S + j];
    float sc = is * g1[j];
    float bb = b1[j] - m * sc;
    const float* w9 = ws + OFF_W + b * REL + j * 9;
#pragma unroll
    for (int k = 0; k < 9; k++) packed[j * 12 + k] = w9[k] * sc;
    packed[j * 12 + 9]  = bb;
    packed[j * 12 + 10] = ws[OFF_ATT + b * D + j];
    packed[j * 12 + 11] = 0.f;
  }
  __syncthreads();
  float taps[3][9];
  float wv[3];
#pragma unroll
  for (int pp = 0; pp < 3; pp++) {
    int p = t + pp * 384;
    bool ok = (p < NP);
    int pc = ok ? p : 0;
    int oy = pc / FW, ox = pc - oy * FW;
#pragma unroll
    for (int kh = 0; kh < 3; kh++)
#pragma unroll
      for (int kw = 0; kw < 3; kw++)
        taps[pp][kh * 3 + kw] = img[(oy + kh) * IMW + ox + kw];
    wv[pp] = ok ? wpl[p] : 0.f;
  }
  float acc = 0.f;
  for (int j = 0; j < RNUM; j++) {
    const float4* rec = (const float4*)&packed[j * 12];
    float4 r0 = rec[0], r1 = rec[1], r2 = rec[2];
    float zs = 0.f;
#pragma unroll
    for (int pp = 0; pp < 3; pp++) {
      float y = r2.y;  // bb
      y = fmaf(taps[pp][0], r0.x, y);
      y = fmaf(taps[pp][1], r0.y, y);
      y = fmaf(taps[pp][2], r0.z, y);
      y = fmaf(taps[pp][3], r0.w, y);
      y = fmaf(taps[pp][4], r1.x, y);
      y = fmaf(taps[pp][5], r1.y, y);
      y = fmaf(taps[pp][6], r1.z, y);
      y = fmaf(taps[pp][7], r1.w, y);
      y = fmaf(taps[pp][8], r2.x, y);
      float z = fmaxf(y, 0.f);
      zs = fmaf(z, wv[pp], zs);
    }
    acc = fmaf(zs, r2.z, acc);  // * aj
  }
  float tot = blockSum384(acc, red);
  if (t == 0) out[b] = tot + ws[OFF_BP];
}

extern "C" void kernel_launch(void* const* d_in, const int* in_sizes, int n_in,
                              void* d_out, int out_size, void* d_ws, size_t ws_size,
                              hipStream_t stream) {
  const int*   r_idx = (const int*)d_in[0];
  const int*   e1 = (const int*)d_in[1];
  const int*   e2 = (const int*)d_in[2];
  const int*   e3 = (const int*)d_in[3];
  const int*   e4 = (const int*)d_in[4];
  const int*   e5 = (const int*)d_in[5];
  const int*   e6 = (const int*)d_in[6];
  const float* E_w  = (const float*)d_in[7];
  const float* R_w  = (const float*)d_in[8];
  const float* bn0g = (const float*)d_in[9];
  const float* bn0b = (const float*)d_in[10];
  const float* bn1g = (const float*)d_in[11];
  const float* bn1b = (const float*)d_in[12];
  const float* bn2g = (const float*)d_in[13];
  const float* bn2b = (const float*)d_in[14];
  const float* Qm   = (const float*)d_in[15];
  const float* Km   = (const float*)d_in[16];
  const float* Vm   = (const float*)d_in[17];
  const float* fc6W = (const float*)d_in[18];
  const float* fc6b = (const float*)d_in[19];
  const float* pv   = (const float*)d_in[20];
  float* ws  = (float*)d_ws;
  float* out = (float*)d_out;

  k_gather48<<<48, 256, 0, stream>>>(e1, e2, e3, e4, e5, e6, E_w, ws);
  k_gather_r<<<512, 256, 0, stream>>>(r_idx, R_w, ws);
  k_bn0_apply<<<400, 256, 0, stream>>>(bn0g, bn0b, ws);
  k_gram<<<B, 256, 0, stream>>>(ws);
  k_bn2_stats<<<8, 256, 0, stream>>>(ws);
  k_q<<<400, 256, 0, stream>>>(Qm, ws);
  k_kv<<<128, 256, 0, stream>>>(Km, Vm, ws);
  k_bn2_apply<<<3600, 256, 0, stream>>>(bn2g, bn2b, ws);
  k_attn<<<256, 256, 0, stream>>>(ws);
  k_bn1_stats<<<RNUM, 256, 0, stream>>>(ws);
  k_wp<<<6, 256, 0, stream>>>(fc6W, fc6b, pv, ws);
  k_final<<<B, 384, 0, stream>>>(bn1g, bn1b, ws, out);
}

// Round 9
// 398.373 us; speedup vs baseline: 1.0762x; 1.0762x over previous
//
#include <hip/hip_runtime.h>

#define DEVFN __device__ __forceinline__

namespace {
constexpr int B    = 512;
constexpr int D    = 200;
constexpr int RNUM = 200;
constexpr int REL  = 1800;
constexpr int FH   = 58, FW = 18, NP = FH * FW;     // 1044
constexpr int IMH  = 60, IMW = 20, IMN = IMH * IMW; // 1200
constexpr float EPS = 1e-5f;
constexpr float INV_SQRT_D = 0.07071067811865475f;  // 1/sqrt(200)

// workspace layout (float offsets)
constexpr int OFF_X    = 0;                      // B*IMN  conv image (bn0'd)
constexpr int OFF_EM   = OFF_X   + B * IMN;      // B*D
constexpr int OFF_R    = OFF_EM  + B * D;        // B*REL
constexpr int OFF_W    = OFF_R   + B * REL;      // B*REL  bn2(r)
constexpr int OFF_Q    = OFF_W   + B * REL;      // B*D
constexpr int OFF_K    = OFF_Q   + B * D;        // B*D    K TRANSPOSED: kT[d][b]
constexpr int OFF_V    = OFF_K   + B * D;        // B*D    V normal: v[b][d]
constexpr int OFF_ATT  = OFF_V   + B * D;        // B*D
constexpr int OFF_S    = OFF_ATT + B * D;        // B*9
constexpr int OFF_G    = OFF_S   + B * 9;        // B*45
constexpr int OFF_BN0P = OFF_G   + B * 45;       // 96 = 6 slots * 8 chunks * {sum,sq}
constexpr int OFF_BN2M = OFF_BN0P + 96;          // REL
constexpr int OFF_BN2S = OFF_BN2M + REL;         // REL
constexpr int OFF_BN1M = OFF_BN2S + REL;         // RNUM
constexpr int OFF_BN1S = OFF_BN1M + RNUM;        // RNUM
constexpr int OFF_WP   = OFF_BN1S + RNUM;        // NP
constexpr int OFF_BP   = OFF_WP  + NP;           // 1
} // namespace

DEVFN float waveSum(float v) {
#pragma unroll
  for (int o = 32; o; o >>= 1) v += __shfl_down(v, o, 64);
  return v;
}
DEVFN float waveMax(float v) {
#pragma unroll
  for (int o = 32; o; o >>= 1) v = fmaxf(v, __shfl_down(v, o, 64));
  return v;
}
DEVFN float blockSum256(float v, float* sm) {
  int lane = threadIdx.x & 63, w = threadIdx.x >> 6;
  v = waveSum(v);
  if (lane == 0) sm[w] = v;
  __syncthreads();
  if (threadIdx.x == 0) sm[4] = sm[0] + sm[1] + sm[2] + sm[3];
  __syncthreads();
  float t = sm[4];
  __syncthreads();
  return t;
}
DEVFN float blockMax256(float v, float* sm) {
  int lane = threadIdx.x & 63, w = threadIdx.x >> 6;
  v = waveMax(v);
  if (lane == 0) sm[w] = v;
  __syncthreads();
  if (threadIdx.x == 0) sm[4] = fmaxf(fmaxf(sm[0], sm[1]), fmaxf(sm[2], sm[3]));
  __syncthreads();
  float t = sm[4];
  __syncthreads();
  return t;
}
DEVFN float blockSum384(float v, float* sm) {
  int lane = threadIdx.x & 63, w = threadIdx.x >> 6;  // 0..5
  v = waveSum(v);
  if (lane == 0) sm[w] = v;
  __syncthreads();
  if (threadIdx.x == 0) sm[6] = sm[0] + sm[1] + sm[2] + sm[3] + sm[4] + sm[5];
  __syncthreads();
  float t = sm[6];
  __syncthreads();
  return t;
}

// ---- K1: gather 6 entity slots (48 blocks: slot x batch-chunk), bn0 partial moments
__global__ __launch_bounds__(256) void k_gather48(
    const int* i1, const int* i2, const int* i3, const int* i4, const int* i5,
    const int* i6, const float* Ew, float* ws) {
  __shared__ float red[8];
  int blk = blockIdx.x, t = threadIdx.x;
  int s = blk >> 3, ch = blk & 7;
  const int* idx = (s == 0) ? i1 : (s == 1) ? i2 : (s == 2) ? i3
                 : (s == 3) ? i4 : (s == 4) ? i5 : i6;
  float sum = 0.f, sq = 0.f;
  for (int ii = t; ii < 64 * D; ii += 256) {
    int b = ch * 64 + ii / D, d = ii % D;
    float v = Ew[(long long)idx[b] * D + d];
    ws[OFF_X + b * IMN + s * D + d] = v;
    sum += v; sq += v * v;
  }
  float ts = blockSum256(sum, red);
  float tq = blockSum256(sq, red);
  if (t == 0) {
    ws[OFF_BN0P + (s * 8 + ch) * 2]     = ts;
    ws[OFF_BN0P + (s * 8 + ch) * 2 + 1] = tq;
  }
}

// ---- K2: gather relation rows (512 blocks, float4)
__global__ __launch_bounds__(256) void k_gather_r(const int* ridx, const float* Rw,
                                                  float* ws) {
  int b = blockIdx.x, t = threadIdx.x;
  const float4* src = (const float4*)(Rw + (long long)ridx[b] * REL);
  float4* dst = (float4*)(ws + OFF_R + b * REL);
  for (int c = t; c < REL / 4; c += 256) dst[c] = src[c];
}

// ---- K3: bn0 finalize + apply + e_mean (400 blocks cover B*D exactly)
__global__ __launch_bounds__(256) void k_bn0_apply(const float* g0, const float* b0, float* ws) {
  __shared__ float stats[12];
  int blk = blockIdx.x, t = threadIdx.x;
  if (t < 6) {
    float sum = 0.f, sq = 0.f;
#pragma unroll
    for (int ch = 0; ch < 8; ch++) {
      sum += ws[OFF_BN0P + (t * 8 + ch) * 2];
      sq  += ws[OFF_BN0P + (t * 8 + ch) * 2 + 1];
    }
    const float n = (float)(B * D);
    float m = sum / n;
    float var = sq / n - m * m;
    stats[2 * t] = m;
    stats[2 * t + 1] = rsqrtf(var + EPS);
  }
  __syncthreads();
  int i = blk * 256 + t;                  // i < B*D always (400*256 == B*D)
  int b = i / D, d = i - b * D;
  float g = g0[0], bb = b0[0];
  float acc = 0.f;
#pragma unroll
  for (int s = 0; s < 6; s++) {
    float v = ws[OFF_X + b * IMN + s * D + d];
    v = (v - stats[2 * s]) * stats[2 * s + 1] * g + bb;
    ws[OFF_X + b * IMN + s * D + d] = v;
    acc += v;
  }
  ws[OFF_EM + i] = acc * (1.f / 6.f);
}

// ---- K4: per-sample patch moments S[9], G[45] (Gram trick for BN1)
__global__ __launch_bounds__(256) void k_gram(float* ws) {
  __shared__ float img[IMN];
  int b = blockIdx.x, t = threadIdx.x;
  for (int i = t; i < IMN; i += 256) img[i] = ws[OFF_X + b * IMN + i];
  __syncthreads();
  float S[9]; float G[45];
#pragma unroll
  for (int a = 0; a < 9; a++) S[a] = 0.f;
#pragma unroll
  for (int u = 0; u < 45; u++) G[u] = 0.f;
  for (int p = t; p < NP; p += 256) {
    int oy = p / FW, ox = p - oy * FW;
    float tp[9];
#pragma unroll
    for (int kh = 0; kh < 3; kh++)
#pragma unroll
      for (int kw = 0; kw < 3; kw++)
        tp[kh * 3 + kw] = img[(oy + kh) * IMW + ox + kw];
    int u = 0;
#pragma unroll
    for (int a = 0; a < 9; a++) {
      S[a] += tp[a];
#pragma unroll
      for (int c = a; c < 9; c++) { G[u] += tp[a] * tp[c]; u++; }
    }
  }
#pragma unroll
  for (int a = 0; a < 9; a++) S[a] = waveSum(S[a]);
#pragma unroll
  for (int u = 0; u < 45; u++) G[u] = waveSum(G[u]);
  __shared__ float part[4][54];
  int lane = t & 63, w = t >> 6;
  if (lane == 0) {
#pragma unroll
    for (int a = 0; a < 9; a++) part[w][a] = S[a];
#pragma unroll
    for (int u = 0; u < 45; u++) part[w][9 + u] = G[u];
  }
  __syncthreads();
  if (t < 54) {
    float v = part[0][t] + part[1][t] + part[2][t] + part[3][t];
    if (t < 9) ws[OFF_S + b * 9 + t] = v;
    else       ws[OFF_G + b * 45 + (t - 9)] = v;
  }
}

// ---- K5: BN2 per-column stats (8 blocks, covers all 1800 columns)
__global__ __launch_bounds__(256) void k_bn2_stats(float* ws) {
  int c = blockIdx.x * 256 + threadIdx.x;
  if (c >= REL) return;
  const float* r = ws + OFF_R;
  float s = 0.f, q = 0.f;
  for (int b = 0; b < B; b++) { float v = r[b * REL + c]; s += v; q += v * v; }
  float m = s / (float)B;
  float var = q / (float)B - m * m;
  ws[OFF_BN2M + c] = m;
  ws[OFF_BN2S + c] = rsqrtf(var + EPS);
}

// ---- K6: q = e_mean @ Q
__global__ __launch_bounds__(256) void k_q(const float* Qm, float* ws) {
  int i = blockIdx.x * 256 + threadIdx.x;
  if (i >= B * D) return;
  int b = i / D, col = i - b * D;
  const float* em = ws + OFF_EM + b * D;
  float a = 0.f;
  for (int d = 0; d < D; d++) a = fmaf(em[d], Qm[d * D + col], a);
  ws[OFF_Q + i] = a;
}

// ---- K7: k = r@K (stored transposed), v = r@V.
// Round-8 PMC showed VGPR=20/VALUBusy=4%: compiler emitted a serial loop —
// one s_waitcnt per load pair at ~200cy L2 latency x 1800 iters = ~150us.
// Fix: EXPLICIT ILP — r rows in LDS, c-loop unrolled x8 so 16 independent
// Km/Vm loads are in flight per burst. Plain stores (atomics were rounds 4-6
// pathology). 128 blocks x 4 rows = minimal L2 re-read volume (369 MB).
__global__ __launch_bounds__(256) void k_kv(const float* Km, const float* Vm, float* ws) {
  __shared__ float rs[4][REL];   // 4 x 1800 x 4B = 28.8 KB
  int bq = blockIdx.x, t = threadIdx.x;
  for (int ii = t; ii < 4 * REL; ii += 256) {
    int u = ii / REL, c = ii - u * REL;
    rs[u][c] = ws[OFF_R + (bq * 4 + u) * REL + c];
  }
  __syncthreads();
  int i = t;
  if (i >= D) return;
  float ak[4] = {0.f, 0.f, 0.f, 0.f}, av[4] = {0.f, 0.f, 0.f, 0.f};
  for (int c0 = 0; c0 < REL; c0 += 8) {     // 225 bursts
    float km[8], vm[8];
#pragma unroll
    for (int cc = 0; cc < 8; cc++) {        // 16 loads issued back-to-back
      km[cc] = Km[(c0 + cc) * D + i];
      vm[cc] = Vm[(c0 + cc) * D + i];
    }
#pragma unroll
    for (int cc = 0; cc < 8; cc++) {
#pragma unroll
      for (int u = 0; u < 4; u++) {
        float rv = rs[u][c0 + cc];
        ak[u] = fmaf(rv, km[cc], ak[u]);
        av[u] = fmaf(rv, vm[cc], av[u]);
      }
    }
  }
#pragma unroll
  for (int u = 0; u < 4; u++) {
    ws[OFF_K + i * B + (bq * 4 + u)] = ak[u];   // kT[d][b] (plain scatter store)
    ws[OFF_V + (bq * 4 + u) * D + i] = av[u];   // v[b][d]  (coalesced)
  }
}

// ---- K8: apply BN2 -> conv weights
__global__ __launch_bounds__(256) void k_bn2_apply(const float* g2, const float* b2, float* ws) {
  int i = blockIdx.x * 256 + threadIdx.x;
  if (i >= B * REL) return;
  int c = i % REL;
  float v = ws[OFF_R + i];
  ws[OFF_W + i] = (v - ws[OFF_BN2M + c]) * ws[OFF_BN2S + c] * g2[c] + b2[c];
}

// ---- K9: attention, 2 queries/block, coalesced kT score loads
__global__ __launch_bounds__(256) void k_attn(float* ws) {
  __shared__ float qs[2][D];
  __shared__ float sc[2][B];
  __shared__ float red[8];
  int blk = blockIdx.x, t = threadIdx.x;
  int b0 = blk * 2;
  for (int i = t; i < 2 * D; i += 256) qs[i / D][i % D] = ws[OFF_Q + b0 * D + i];
  __syncthreads();
  const float* kT = ws + OFF_K;
  float lmax0 = -1e30f, lmax1 = -1e30f;
#pragma unroll
  for (int jj = 0; jj < 2; jj++) {
    int j = t + jj * 256;
    float a0 = 0.f, a1 = 0.f;
    for (int d = 0; d < D; d++) {
      float kv = kT[d * B + j];
      a0 = fmaf(qs[0][d], kv, a0);
      a1 = fmaf(qs[1][d], kv, a1);
    }
    a0 *= INV_SQRT_D; a1 *= INV_SQRT_D;
    sc[0][j] = a0; sc[1][j] = a1;
    lmax0 = fmaxf(lmax0, a0); lmax1 = fmaxf(lmax1, a1);
  }
  float gmax0 = blockMax256(lmax0, red);
  float gmax1 = blockMax256(lmax1, red);
  float lsum0 = 0.f, lsum1 = 0.f;
#pragma unroll
  for (int jj = 0; jj < 2; jj++) {
    int j = t + jj * 256;
    float e0 = __expf(sc[0][j] - gmax0);
    float e1 = __expf(sc[1][j] - gmax1);
    sc[0][j] = e0; sc[1][j] = e1;
    lsum0 += e0; lsum1 += e1;
  }
  float tot0 = blockSum256(lsum0, red);
  float tot1 = blockSum256(lsum1, red);
  float inv0 = 1.f / tot0, inv1 = 1.f / tot1;
  if (t < D) {
    const float* v = ws + OFF_V;
    float a0 = 0.f, a1 = 0.f;
#pragma unroll 4
    for (int j = 0; j < B; j++) {
      float vv = v[j * D + t];
      a0 = fmaf(sc[0][j], vv, a0);
      a1 = fmaf(sc[1][j], vv, a1);
    }
    ws[OFF_ATT + b0 * D + t]       = a0 * inv0;
    ws[OFF_ATT + (b0 + 1) * D + t] = a1 * inv1;
  }
}

// ---- K10: BN1 per-channel stats from (w, S, G)
__global__ __launch_bounds__(256) void k_bn1_stats(float* ws) {
  __shared__ float red[8];
  int j = blockIdx.x, t = threadIdx.x;
  float s = 0.f, q = 0.f;
  for (int b = t; b < B; b += 256) {
    const float* w9 = ws + OFF_W + b * REL + j * 9;
    float wr[9];
#pragma unroll
    for (int k = 0; k < 9; k++) wr[k] = w9[k];
    const float* Sb = ws + OFF_S + b * 9;
    const float* Gb = ws + OFF_G + b * 45;
    float sl = 0.f;
#pragma unroll
    for (int k = 0; k < 9; k++) sl = fmaf(wr[k], Sb[k], sl);
    float ql = 0.f;
    int u = 0;
#pragma unroll
    for (int a = 0; a < 9; a++) {
      ql = fmaf(wr[a] * wr[a], Gb[u], ql); u++;
#pragma unroll
      for (int c = a + 1; c < 9; c++) { ql = fmaf(2.f * wr[a] * wr[c], Gb[u], ql); u++; }
    }
    s += sl; q += ql;
  }
  float ts = blockSum256(s, red);
  float tq = blockSum256(q, red);
  if (t == 0) {
    const float N = (float)B * (float)NP;
    float m = ts / N;
    float var = tq / N - m * m;
    ws[OFF_BN1M + j] = m;
    ws[OFF_BN1S + j] = rsqrtf(var + EPS);
  }
}

// ---- K11: wp = fc6_W^T @ p , bp = fc6_b . p
__global__ __launch_bounds__(256) void k_wp(const float* W, const float* bias,
                                            const float* pv, float* ws) {
  int p = blockIdx.x * 256 + threadIdx.x;
  if (p < NP) {
    float a = 0.f;
    for (int n = 0; n < 100; n++) a = fmaf(W[n * NP + p], pv[n], a);
    ws[OFF_WP + p] = a;
  } else if (p == NP) {
    float a = 0.f;
    for (int n = 0; n < 100; n++) a = fmaf(bias[n], pv[n], a);
    ws[OFF_BP] = a;
  }
}

// ---- K12: final fused conv + BN1 + relu + attention + spatial fc reduce (384 thr)
__global__ __launch_bounds__(384) void k_final(const float* g1, const float* b1,
                                               float* ws, float* out) {
  __shared__ float img[IMN];
  __shared__ float wpl[NP];
  __shared__ float packed[RNUM * 12];   // [w0..w8]*sc, bb, aj, pad
  __shared__ float red[8];
  int b = blockIdx.x, t = threadIdx.x;
  for (int i = t; i < IMN; i += 384) img[i] = ws[OFF_X + b * IMN + i];
  for (int i = t; i < NP; i += 384) wpl[i] = ws[OFF_WP + i];
  if (t < RNUM) {
    int j = t;
    float m = ws[OFF_BN1M + j], is = ws[OFF_BN1S + j];
    float sc = is * g1[j];
    float bb = b1[j] - m * sc;
    const float* w9 = ws + OFF_W + b * REL + j * 9;
#pragma unroll
    for (int k = 0; k < 9; k++) packed[j * 12 + k] = w9[k] * sc;
    packed[j * 12 + 9]  = bb;
    packed[j * 12 + 10] = ws[OFF_ATT + b * D + j];
    packed[j * 12 + 11] = 0.f;
  }
  __syncthreads();
  float taps[3][9];
  float wv[3];
#pragma unroll
  for (int pp = 0; pp < 3; pp++) {
    int p = t + pp * 384;
    bool ok = (p < NP);
    int pc = ok ? p : 0;
    int oy = pc / FW, ox = pc - oy * FW;
#pragma unroll
    for (int kh = 0; kh < 3; kh++)
#pragma unroll
      for (int kw = 0; kw < 3; kw++)
        taps[pp][kh * 3 + kw] = img[(oy + kh) * IMW + ox + kw];
    wv[pp] = ok ? wpl[p] : 0.f;
  }
  float acc = 0.f;
  for (int j = 0; j < RNUM; j++) {
    const float4* rec = (const float4*)&packed[j * 12];
    float4 r0 = rec[0], r1 = rec[1], r2 = rec[2];
    float zs = 0.f;
#pragma unroll
    for (int pp = 0; pp < 3; pp++) {
      float y = r2.y;  // bb
      y = fmaf(taps[pp][0], r0.x, y);
      y = fmaf(taps[pp][1], r0.y, y);
      y = fmaf(taps[pp][2], r0.z, y);
      y = fmaf(taps[pp][3], r0.w, y);
      y = fmaf(taps[pp][4], r1.x, y);
      y = fmaf(taps[pp][5], r1.y, y);
      y = fmaf(taps[pp][6], r1.z, y);
      y = fmaf(taps[pp][7], r1.w, y);
      y = fmaf(taps[pp][8], r2.x, y);
      float z = fmaxf(y, 0.f);
      zs = fmaf(z, wv[pp], zs);
    }
    acc = fmaf(zs, r2.z, acc);  // * aj
  }
  float tot = blockSum384(acc, red);
  if (t == 0) out[b] = tot + ws[OFF_BP];
}

extern "C" void kernel_launch(void* const* d_in, const int* in_sizes, int n_in,
                              void* d_out, int out_size, void* d_ws, size_t ws_size,
                              hipStream_t stream) {
  const int*   r_idx = (const int*)d_in[0];
  const int*   e1 = (const int*)d_in[1];
  const int*   e2 = (const int*)d_in[2];
  const int*   e3 = (const int*)d_in[3];
  const int*   e4 = (const int*)d_in[4];
  const int*   e5 = (const int*)d_in[5];
  const int*   e6 = (const int*)d_in[6];
  const float* E_w  = (const float*)d_in[7];
  const float* R_w  = (const float*)d_in[8];
  const float* bn0g = (const float*)d_in[9];
  const float* bn0b = (const float*)d_in[10];
  const float* bn1g = (const float*)d_in[11];
  const float* bn1b = (const float*)d_in[12];
  const float* bn2g = (const float*)d_in[13];
  const float* bn2b = (const float*)d_in[14];
  const float* Qm   = (const float*)d_in[15];
  const float* Km   = (const float*)d_in[16];
  const float* Vm   = (const float*)d_in[17];
  const float* fc6W = (const float*)d_in[18];
  const float* fc6b = (const float*)d_in[19];
  const float* pv   = (const float*)d_in[20];
  float* ws  = (float*)d_ws;
  float* out = (float*)d_out;

  k_gather48<<<48, 256, 0, stream>>>(e1, e2, e3, e4, e5, e6, E_w, ws);
  k_gather_r<<<512, 256, 0, stream>>>(r_idx, R_w, ws);
  k_bn0_apply<<<400, 256, 0, stream>>>(bn0g, bn0b, ws);
  k_gram<<<B, 256, 0, stream>>>(ws);
  k_bn2_stats<<<8, 256, 0, stream>>>(ws);
  k_q<<<400, 256, 0, stream>>>(Qm, ws);
  k_kv<<<128, 256, 0, stream>>>(Km, Vm, ws);
  k_bn2_apply<<<3600, 256, 0, stream>>>(bn2g, bn2b, ws);
  k_attn<<<256, 256, 0, stream>>>(ws);
  k_bn1_stats<<<RNUM, 256, 0, stream>>>(ws);
  k_wp<<<6, 256, 0, stream>>>(fc6W, fc6b, pv, ws);
  k_final<<<B, 384, 0, stream>>>(bn1g, bn1b, ws, out);
}

// Round 11
// 340.760 us; speedup vs baseline: 1.2581x; 1.1691x over previous
//
#include <hip/hip_runtime.h>

#define DEVFN __device__ __forceinline__

namespace {
constexpr int B    = 512;
constexpr int D    = 200;
constexpr int RNUM = 200;
constexpr int REL  = 1800;
constexpr int FH   = 58, FW = 18, NP = FH * FW;     // 1044
constexpr int IMH  = 60, IMW = 20, IMN = IMH * IMW; // 1200
constexpr float EPS = 1e-5f;
constexpr float INV_SQRT_D = 0.07071067811865475f;  // 1/sqrt(200)

// k_kv split-K: 4 rows x 5 REL-chunks, 640 blocks (2.5 waves/SIMD of TLP)
constexpr int KV_RB   = 4;
constexpr int KV_CH   = 5;
constexpr int KV_CLEN = REL / KV_CH;   // 360 = 8*45

// workspace layout (float offsets)
constexpr int OFF_X    = 0;                      // B*IMN  conv image (bn0'd)
constexpr int OFF_EM   = OFF_X   + B * IMN;      // B*D
constexpr int OFF_R    = OFF_EM  + B * D;        // B*REL
constexpr int OFF_W    = OFF_R   + B * REL;      // B*REL  bn2(r)
constexpr int OFF_Q    = OFF_W   + B * REL;      // B*D
constexpr int OFF_K    = OFF_Q   + B * D;        // B*D    K TRANSPOSED: kT[d][b]
constexpr int OFF_V    = OFF_K   + B * D;        // B*D    V normal: v[b][d]
constexpr int OFF_ATT  = OFF_V   + B * D;        // B*D
constexpr int OFF_S    = OFF_ATT + B * D;        // B*9
constexpr int OFF_G    = OFF_S   + B * 9;        // B*45
constexpr int OFF_BN0P = OFF_G   + B * 45;       // 96 = 6 slots * 8 chunks * {sum,sq}
constexpr int OFF_BN2M = OFF_BN0P + 96;          // REL
constexpr int OFF_BN2S = OFF_BN2M + REL;         // REL
constexpr int OFF_BN1M = OFF_BN2S + REL;         // RNUM
constexpr int OFF_BN1S = OFF_BN1M + RNUM;        // RNUM
constexpr int OFF_WP   = OFF_BN1S + RNUM;        // NP
constexpr int OFF_BP   = OFF_WP  + NP;           // 1
constexpr int OFF_PK   = ((OFF_BP + 1 + 3) / 4) * 4;  // 4 x B*D partial K (chunks 1-4)
constexpr int OFF_PV   = OFF_PK + 4 * B * D;           // 4 x B*D partial V
// total = OFF_PV + 4*B*D = ~3.82M floats = 15.3 MB
} // namespace

DEVFN float waveSum(float v) {
#pragma unroll
  for (int o = 32; o; o >>= 1) v += __shfl_down(v, o, 64);
  return v;
}
DEVFN float waveMax(float v) {
#pragma unroll
  for (int o = 32; o; o >>= 1) v = fmaxf(v, __shfl_down(v, o, 64));
  return v;
}
DEVFN float blockSum256(float v, float* sm) {
  int lane = threadIdx.x & 63, w = threadIdx.x >> 6;
  v = waveSum(v);
  if (lane == 0) sm[w] = v;
  __syncthreads();
  if (threadIdx.x == 0) sm[4] = sm[0] + sm[1] + sm[2] + sm[3];
  __syncthreads();
  float t = sm[4];
  __syncthreads();
  return t;
}
DEVFN float blockMax256(float v, float* sm) {
  int lane = threadIdx.x & 63, w = threadIdx.x >> 6;
  v = waveMax(v);
  if (lane == 0) sm[w] = v;
  __syncthreads();
  if (threadIdx.x == 0) sm[4] = fmaxf(fmaxf(sm[0], sm[1]), fmaxf(sm[2], sm[3]));
  __syncthreads();
  float t = sm[4];
  __syncthreads();
  return t;
}
DEVFN float blockSum384(float v, float* sm) {
  int lane = threadIdx.x & 63, w = threadIdx.x >> 6;  // 0..5
  v = waveSum(v);
  if (lane == 0) sm[w] = v;
  __syncthreads();
  if (threadIdx.x == 0) sm[6] = sm[0] + sm[1] + sm[2] + sm[3] + sm[4] + sm[5];
  __syncthreads();
  float t = sm[6];
  __syncthreads();
  return t;
}

// ---- K1: gather 6 entity slots (48 blocks: slot x batch-chunk), bn0 partial moments
__global__ __launch_bounds__(256) void k_gather48(
    const int* i1, const int* i2, const int* i3, const int* i4, const int* i5,
    const int* i6, const float* Ew, float* ws) {
  __shared__ float red[8];
  int blk = blockIdx.x, t = threadIdx.x;
  int s = blk >> 3, ch = blk & 7;
  const int* idx = (s == 0) ? i1 : (s == 1) ? i2 : (s == 2) ? i3
                 : (s == 3) ? i4 : (s == 4) ? i5 : i6;
  float sum = 0.f, sq = 0.f;
  for (int ii = t; ii < 64 * D; ii += 256) {
    int b = ch * 64 + ii / D, d = ii % D;
    float v = Ew[(long long)idx[b] * D + d];
    ws[OFF_X + b * IMN + s * D + d] = v;
    sum += v; sq += v * v;
  }
  float ts = blockSum256(sum, red);
  float tq = blockSum256(sq, red);
  if (t == 0) {
    ws[OFF_BN0P + (s * 8 + ch) * 2]     = ts;
    ws[OFF_BN0P + (s * 8 + ch) * 2 + 1] = tq;
  }
}

// ---- K2: gather relation rows (512 blocks, float4)
__global__ __launch_bounds__(256) void k_gather_r(const int* ridx, const float* Rw,
                                                  float* ws) {
  int b = blockIdx.x, t = threadIdx.x;
  const float4* src = (const float4*)(Rw + (long long)ridx[b] * REL);
  float4* dst = (float4*)(ws + OFF_R + b * REL);
  for (int c = t; c < REL / 4; c += 256) dst[c] = src[c];
}

// ---- K3: bn0 finalize + apply + e_mean (400 blocks cover B*D exactly)
__global__ __launch_bounds__(256) void k_bn0_apply(const float* g0, const float* b0, float* ws) {
  __shared__ float stats[12];
  int blk = blockIdx.x, t = threadIdx.x;
  if (t < 6) {
    float sum = 0.f, sq = 0.f;
#pragma unroll
    for (int ch = 0; ch < 8; ch++) {
      sum += ws[OFF_BN0P + (t * 8 + ch) * 2];
      sq  += ws[OFF_BN0P + (t * 8 + ch) * 2 + 1];
    }
    const float n = (float)(B * D);
    float m = sum / n;
    float var = sq / n - m * m;
    stats[2 * t] = m;
    stats[2 * t + 1] = rsqrtf(var + EPS);
  }
  __syncthreads();
  int i = blk * 256 + t;                  // i < B*D always (400*256 == B*D)
  int b = i / D, d = i - b * D;
  float g = g0[0], bb = b0[0];
  float acc = 0.f;
#pragma unroll
  for (int s = 0; s < 6; s++) {
    float v = ws[OFF_X + b * IMN + s * D + d];
    v = (v - stats[2 * s]) * stats[2 * s + 1] * g + bb;
    ws[OFF_X + b * IMN + s * D + d] = v;
    acc += v;
  }
  ws[OFF_EM + i] = acc * (1.f / 6.f);
}

// ---- K4: per-sample patch moments S[9], G[45] (Gram trick for BN1)
__global__ __launch_bounds__(256) void k_gram(float* ws) {
  __shared__ float img[IMN];
  int b = blockIdx.x, t = threadIdx.x;
  for (int i = t; i < IMN; i += 256) img[i] = ws[OFF_X + b * IMN + i];
  __syncthreads();
  float S[9]; float G[45];
#pragma unroll
  for (int a = 0; a < 9; a++) S[a] = 0.f;
#pragma unroll
  for (int u = 0; u < 45; u++) G[u] = 0.f;
  for (int p = t; p < NP; p += 256) {
    int oy = p / FW, ox = p - oy * FW;
    float tp[9];
#pragma unroll
    for (int kh = 0; kh < 3; kh++)
#pragma unroll
      for (int kw = 0; kw < 3; kw++)
        tp[kh * 3 + kw] = img[(oy + kh) * IMW + ox + kw];
    int u = 0;
#pragma unroll
    for (int a = 0; a < 9; a++) {
      S[a] += tp[a];
#pragma unroll
      for (int c = a; c < 9; c++) { G[u] += tp[a] * tp[c]; u++; }
    }
  }
#pragma unroll
  for (int a = 0; a < 9; a++) S[a] = waveSum(S[a]);
#pragma unroll
  for (int u = 0; u < 45; u++) G[u] = waveSum(G[u]);
  __shared__ float part[4][54];
  int lane = t & 63, w = t >> 6;
  if (lane == 0) {
#pragma unroll
    for (int a = 0; a < 9; a++) part[w][a] = S[a];
#pragma unroll
    for (int u = 0; u < 45; u++) part[w][9 + u] = G[u];
  }
  __syncthreads();
  if (t < 54) {
    float v = part[0][t] + part[1][t] + part[2][t] + part[3][t];
    if (t < 9) ws[OFF_S + b * 9 + t] = v;
    else       ws[OFF_G + b * 45 + (t - 9)] = v;
  }
}

// ---- K5: BN2 per-column stats (8 blocks, covers all 1800 columns)
__global__ __launch_bounds__(256) void k_bn2_stats(float* ws) {
  int c = blockIdx.x * 256 + threadIdx.x;
  if (c >= REL) return;
  const float* r = ws + OFF_R;
  float s = 0.f, q = 0.f;
  for (int b = 0; b < B; b++) { float v = r[b * REL + c]; s += v; q += v * v; }
  float m = s / (float)B;
  float var = q / (float)B - m * m;
  ws[OFF_BN2M + c] = m;
  ws[OFF_BN2S + c] = rsqrtf(var + EPS);
}

// ---- K6: q = e_mean @ Q
__global__ __launch_bounds__(256) void k_q(const float* Qm, float* ws) {
  int i = blockIdx.x * 256 + threadIdx.x;
  if (i >= B * D) return;
  int b = i / D, col = i - b * D;
  const float* em = ws + OFF_EM + b * D;
  float a = 0.f;
  for (int d = 0; d < D; d++) a = fmaf(em[d], Qm[d * D + col], a);
  ws[OFF_Q + i] = a;
}

// ---- K7: k/v GEMM, split-K over 5 REL-chunks x 128 row-groups = 640 blocks.
// Round-9 PMC: Occupancy 5.8% (1 wave/SIMD) was the latency-exposure root cause —
// ILP alone couldn't hide ~300cy L2 latency. 640 blocks = 2.5 waves/SIMD of TLP.
// Chunk 0 -> K/V direct; chunks 1-4 -> private partials (NO atomics); k_kvfix sums.
// r staged in LDS packed [c][4] so 4 row-values = one ds_read_b128 broadcast.
__global__ __launch_bounds__(256) void k_kv(const float* Km, const float* Vm, float* ws) {
  __shared__ float rs[KV_CLEN][KV_RB];   // 360 x 4 x 4B = 5.76 KB
  int blk = blockIdx.x, t = threadIdx.x;
  int g = blk / KV_CH, ch = blk % KV_CH;
  int c0 = ch * KV_CLEN;
  for (int ii = t; ii < KV_RB * KV_CLEN; ii += 256) {
    int c = ii >> 2, u = ii & 3;
    rs[c][u] = ws[OFF_R + (g * KV_RB + u) * REL + c0 + c];
  }
  __syncthreads();
  int i = t;
  if (i >= D) return;
  float ak[4] = {0.f, 0.f, 0.f, 0.f}, av[4] = {0.f, 0.f, 0.f, 0.f};
  for (int cb = 0; cb < KV_CLEN; cb += 8) {   // 45 bursts
    float km[8], vm[8];
#pragma unroll
    for (int cc = 0; cc < 8; cc++) {          // 16 independent loads in flight
      km[cc] = Km[(c0 + cb + cc) * D + i];
      vm[cc] = Vm[(c0 + cb + cc) * D + i];
    }
#pragma unroll
    for (int cc = 0; cc < 8; cc++) {
      float4 rv = *(const float4*)&rs[cb + cc][0];
      ak[0] = fmaf(rv.x, km[cc], ak[0]); av[0] = fmaf(rv.x, vm[cc], av[0]);
      ak[1] = fmaf(rv.y, km[cc], ak[1]); av[1] = fmaf(rv.y, vm[cc], av[1]);
      ak[2] = fmaf(rv.z, km[cc], ak[2]); av[2] = fmaf(rv.z, vm[cc], av[2]);
      ak[3] = fmaf(rv.w, km[cc], ak[3]); av[3] = fmaf(rv.w, vm[cc], av[3]);
    }
  }
  float* dk = (ch == 0) ? (ws + OFF_K) : (ws + OFF_PK + (ch - 1) * (B * D));
  float* dv = (ch == 0) ? (ws + OFF_V) : (ws + OFF_PV + (ch - 1) * (B * D));
#pragma unroll
  for (int u = 0; u < 4; u++) {
    dk[i * B + (g * 4 + u)] = ak[u];   // kT[d][b] layout in every buffer
    dv[(g * 4 + u) * D + i] = av[u];   // v[b][d]
  }
}

// ---- K7b: sum the 4 split-K partials into K/V (800 blocks, plain elementwise)
__global__ __launch_bounds__(256) void k_kvfix(float* ws) {
  int i = blockIdx.x * 256 + threadIdx.x;   // covers 2*B*D = 204800 exactly
  if (i < B * D) {
    float a = ws[OFF_K + i];
#pragma unroll
    for (int s = 0; s < 4; s++) a += ws[OFF_PK + s * (B * D) + i];
    ws[OFF_K + i] = a;
  } else {
    int j = i - B * D;
    float a = ws[OFF_V + j];
#pragma unroll
    for (int s = 0; s < 4; s++) a += ws[OFF_PV + s * (B * D) + j];
    ws[OFF_V + j] = a;
  }
}

// ---- K8: apply BN2 -> conv weights
__global__ __launch_bounds__(256) void k_bn2_apply(const float* g2, const float* b2, float* ws) {
  int i = blockIdx.x * 256 + threadIdx.x;
  if (i >= B * REL) return;
  int c = i % REL;
  float v = ws[OFF_R + i];
  ws[OFF_W + i] = (v - ws[OFF_BN2M + c]) * ws[OFF_BN2S + c] * g2[c] + b2[c];
}

// ---- K9: attention, 2 queries/block, coalesced kT score loads
__global__ __launch_bounds__(256) void k_attn(float* ws) {
  __shared__ float qs[2][D];
  __shared__ float sc[2][B];
  __shared__ float red[8];
  int blk = blockIdx.x, t = threadIdx.x;
  int b0 = blk * 2;
  for (int i = t; i < 2 * D; i += 256) qs[i / D][i % D] = ws[OFF_Q + b0 * D + i];
  __syncthreads();
  const float* kT = ws + OFF_K;
  float lmax0 = -1e30f, lmax1 = -1e30f;
#pragma unroll
  for (int jj = 0; jj < 2; jj++) {
    int j = t + jj * 256;
    float a0 = 0.f, a1 = 0.f;
    for (int d = 0; d < D; d++) {
      float kv = kT[d * B + j];
      a0 = fmaf(qs[0][d], kv, a0);
      a1 = fmaf(qs[1][d], kv, a1);
    }
    a0 *= INV_SQRT_D; a1 *= INV_SQRT_D;
    sc[0][j] = a0; sc[1][j] = a1;
    lmax0 = fmaxf(lmax0, a0); lmax1 = fmaxf(lmax1, a1);
  }
  float gmax0 = blockMax256(lmax0, red);
  float gmax1 = blockMax256(lmax1, red);
  float lsum0 = 0.f, lsum1 = 0.f;
#pragma unroll
  for (int jj = 0; jj < 2; jj++) {
    int j = t + jj * 256;
    float e0 = __expf(sc[0][j] - gmax0);
    float e1 = __expf(sc[1][j] - gmax1);
    sc[0][j] = e0; sc[1][j] = e1;
    lsum0 += e0; lsum1 += e1;
  }
  float tot0 = blockSum256(lsum0, red);
  float tot1 = blockSum256(lsum1, red);
  float inv0 = 1.f / tot0, inv1 = 1.f / tot1;
  if (t < D) {
    const float* v = ws + OFF_V;
    float a0 = 0.f, a1 = 0.f;
#pragma unroll 4
    for (int j = 0; j < B; j++) {
      float vv = v[j * D + t];
      a0 = fmaf(sc[0][j], vv, a0);
      a1 = fmaf(sc[1][j], vv, a1);
    }
    ws[OFF_ATT + b0 * D + t]       = a0 * inv0;
    ws[OFF_ATT + (b0 + 1) * D + t] = a1 * inv1;
  }
}

// ---- K10: BN1 per-channel stats from (w, S, G)
__global__ __launch_bounds__(256) void k_bn1_stats(float* ws) {
  __shared__ float red[8];
  int j = blockIdx.x, t = threadIdx.x;
  float s = 0.f, q = 0.f;
  for (int b = t; b < B; b += 256) {
    const float* w9 = ws + OFF_W + b * REL + j * 9;
    float wr[9];
#pragma unroll
    for (int k = 0; k < 9; k++) wr[k] = w9[k];
    const float* Sb = ws + OFF_S + b * 9;
    const float* Gb = ws + OFF_G + b * 45;
    float sl = 0.f;
#pragma unroll
    for (int k = 0; k < 9; k++) sl = fmaf(wr[k], Sb[k], sl);
    float ql = 0.f;
    int u = 0;
#pragma unroll
    for (int a = 0; a < 9; a++) {
      ql = fmaf(wr[a] * wr[a], Gb[u], ql); u++;
#pragma unroll
      for (int c = a + 1; c < 9; c++) { ql = fmaf(2.f * wr[a] * wr[c], Gb[u], ql); u++; }
    }
    s += sl; q += ql;
  }
  float ts = blockSum256(s, red);
  float tq = blockSum256(q, red);
  if (t == 0) {
    const float N = (float)B * (float)NP;
    float m = ts / N;
    float var = tq / N - m * m;
    ws[OFF_BN1M + j] = m;
    ws[OFF_BN1S + j] = rsqrtf(var + EPS);
  }
}

// ---- K11: wp = fc6_W^T @ p , bp = fc6_b . p
__global__ __launch_bounds__(256) void k_wp(const float* W, const float* bias,
                                            const float* pv, float* ws) {
  int p = blockIdx.x * 256 + threadIdx.x;
  if (p < NP) {
    float a = 0.f;
    for (int n = 0; n < 100; n++) a = fmaf(W[n * NP + p], pv[n], a);
    ws[OFF_WP + p] = a;
  } else if (p == NP) {
    float a = 0.f;
    for (int n = 0; n < 100; n++) a = fmaf(bias[n], pv[n], a);
    ws[OFF_BP] = a;
  }
}

// ---- K12: final fused conv + BN1 + relu + attention + spatial fc reduce (384 thr)
__global__ __launch_bounds__(384) void k_final(const float* g1, const float* b1,
                                               float* ws, float* out) {
  __shared__ float img[IMN];
  __shared__ float wpl[NP];
  __shared__ float packed[RNUM * 12];   // [w0..w8]*sc, bb, aj, pad
  __shared__ float red[8];
  int b = blockIdx.x, t = threadIdx.x;
  for (int i = t; i < IMN; i += 384) img[i] = ws[OFF_X + b * IMN + i];
  for (int i = t; i < NP; i += 384) wpl[i] = ws[OFF_WP + i];
  if (t < RNUM) {
    int j = t;
    float m = ws[OFF_BN1M + j], is = ws[OFF_BN1S + j];
    float sc = is * g1[j];
    float bb = b1[j] - m * sc;
    const float* w9 = ws + OFF_W + b * REL + j * 9;
#pragma unroll
    for (int k = 0; k < 9; k++) packed[j * 12 + k] = w9[k] * sc;
    packed[j * 12 + 9]  = bb;
    packed[j * 12 + 10] = ws[OFF_ATT + b * D + j];
    packed[j * 12 + 11] = 0.f;
  }
  __syncthreads();
  float taps[3][9];
  float wv[3];
#pragma unroll
  for (int pp = 0; pp < 3; pp++) {
    int p = t + pp * 384;
    bool ok = (p < NP);
    int pc = ok ? p : 0;
    int oy = pc / FW, ox = pc - oy * FW;
#pragma unroll
    for (int kh = 0; kh < 3; kh++)
#pragma unroll
      for (int kw = 0; kw < 3; kw++)
        taps[pp][kh * 3 + kw] = img[(oy + kh) * IMW + ox + kw];
    wv[pp] = ok ? wpl[p] : 0.f;
  }
  float acc = 0.f;
  for (int j = 0; j < RNUM; j++) {
    const float4* rec = (const float4*)&packed[j * 12];
    float4 r0 = rec[0], r1 = rec[1], r2 = rec[2];
    float zs = 0.f;
#pragma unroll
    for (int pp = 0; pp < 3; pp++) {
      float y = r2.y;  // bb
      y = fmaf(taps[pp][0], r0.x, y);
      y = fmaf(taps[pp][1], r0.y, y);
      y = fmaf(taps[pp][2], r0.z, y);
      y = fmaf(taps[pp][3], r0.w, y);
      y = fmaf(taps[pp][4], r1.x, y);
      y = fmaf(taps[pp][5], r1.y, y);
      y = fmaf(taps[pp][6], r1.z, y);
      y = fmaf(taps[pp][7], r1.w, y);
      y = fmaf(taps[pp][8], r2.x, y);
      float z = fmaxf(y, 0.f);
      zs = fmaf(z, wv[pp], zs);
    }
    acc = fmaf(zs, r2.z, acc);  // * aj
  }
  float tot = blockSum384(acc, red);
  if (t == 0) out[b] = tot + ws[OFF_BP];
}

extern "C" void kernel_launch(void* const* d_in, const int* in_sizes, int n_in,
                              void* d_out, int out_size, void* d_ws, size_t ws_size,
                              hipStream_t stream) {
  const int*   r_idx = (const int*)d_in[0];
  const int*   e1 = (const int*)d_in[1];
  const int*   e2 = (const int*)d_in[2];
  const int*   e3 = (const int*)d_in[3];
  const int*   e4 = (const int*)d_in[4];
  const int*   e5 = (const int*)d_in[5];
  const int*   e6 = (const int*)d_in[6];
  const float* E_w  = (const float*)d_in[7];
  const float* R_w  = (const float*)d_in[8];
  const float* bn0g = (const float*)d_in[9];
  const float* bn0b = (const float*)d_in[10];
  const float* bn1g = (const float*)d_in[11];
  const float* bn1b = (const float*)d_in[12];
  const float* bn2g = (const float*)d_in[13];
  const float* bn2b = (const float*)d_in[14];
  const float* Qm   = (const float*)d_in[15];
  const float* Km   = (const float*)d_in[16];
  const float* Vm   = (const float*)d_in[17];
  const float* fc6W = (const float*)d_in[18];
  const float* fc6b = (const float*)d_in[19];
  const float* pv   = (const float*)d_in[20];
  float* ws  = (float*)d_ws;
  float* out = (float*)d_out;

  k_gather48<<<48, 256, 0, stream>>>(e1, e2, e3, e4, e5, e6, E_w, ws);
  k_gather_r<<<512, 256, 0, stream>>>(r_idx, R_w, ws);
  k_bn0_apply<<<400, 256, 0, stream>>>(bn0g, bn0b, ws);
  k_gram<<<B, 256, 0, stream>>>(ws);
  k_bn2_stats<<<8, 256, 0, stream>>>(ws);
  k_q<<<400, 256, 0, stream>>>(Qm, ws);
  k_kv<<<128 * KV_CH, 256, 0, stream>>>(Km, Vm, ws);
  k_kvfix<<<800, 256, 0, stream>>>(ws);
  k_bn2_apply<<<3600, 256, 0, stream>>>(bn2g, bn2b, ws);
  k_attn<<<256, 256, 0, stream>>>(ws);
  k_bn1_stats<<<RNUM, 256, 0, stream>>>(ws);
  k_wp<<<6, 256, 0, stream>>>(fc6W, fc6b, pv, ws);
  k_final<<<B, 384, 0, stream>>>(bn1g, bn1b, ws, out);
}

// Round 12
// 310.275 us; speedup vs baseline: 1.3817x; 1.0983x over previous
//
#include <hip/hip_runtime.h>

#define DEVFN __device__ __forceinline__

namespace {
constexpr int B    = 512;
constexpr int D    = 200;
constexpr int RNUM = 200;
constexpr int REL  = 1800;
constexpr int FH   = 58, FW = 18, NP = FH * FW;     // 1044
constexpr int IMH  = 60, IMW = 20, IMN = IMH * IMW; // 1200
constexpr float EPS = 1e-5f;
constexpr float INV_SQRT_D = 0.07071067811865475f;  // 1/sqrt(200)

// k_kv split-K: 4 rows x 5 REL-chunks, 640 blocks (2.5 waves/SIMD of TLP)
constexpr int KV_RB   = 4;
constexpr int KV_CH   = 5;
constexpr int KV_CLEN = REL / KV_CH;   // 360 = 8*45

// workspace layout (float offsets)
constexpr int OFF_X    = 0;                      // B*IMN  conv image (bn0'd)
constexpr int OFF_EM   = OFF_X   + B * IMN;      // B*D
constexpr int OFF_R    = OFF_EM  + B * D;        // B*REL
constexpr int OFF_W    = OFF_R   + B * REL;      // B*REL  bn2(r)
constexpr int OFF_Q    = OFF_W   + B * REL;      // B*D
constexpr int OFF_K    = OFF_Q   + B * D;        // B*D    K TRANSPOSED: kT[d][b]
constexpr int OFF_V    = OFF_K   + B * D;        // B*D    V normal: v[b][d]
constexpr int OFF_ATT  = OFF_V   + B * D;        // B*D
constexpr int OFF_S    = OFF_ATT + B * D;        // B*9
constexpr int OFF_G    = OFF_S   + B * 9;        // B*45
constexpr int OFF_BN0P = OFF_G   + B * 45;       // 96 = 6 slots * 8 chunks * {sum,sq}
constexpr int OFF_BN2M = OFF_BN0P + 96;          // REL
constexpr int OFF_BN2S = OFF_BN2M + REL;         // REL
constexpr int OFF_BN1M = OFF_BN2S + REL;         // RNUM
constexpr int OFF_BN1S = OFF_BN1M + RNUM;        // RNUM
constexpr int OFF_WP   = OFF_BN1S + RNUM;        // NP
constexpr int OFF_BP   = OFF_WP  + NP;           // 1
constexpr int OFF_PK   = ((OFF_BP + 1 + 3) / 4) * 4;  // 4 x B*D partial K (chunks 1-4)
constexpr int OFF_PV   = OFF_PK + 4 * B * D;           // 4 x B*D partial V
// total = OFF_PV + 4*B*D = ~3.82M floats = 15.3 MB
} // namespace

DEVFN float waveSum(float v) {
#pragma unroll
  for (int o = 32; o; o >>= 1) v += __shfl_down(v, o, 64);
  return v;
}
DEVFN float waveMax(float v) {
#pragma unroll
  for (int o = 32; o; o >>= 1) v = fmaxf(v, __shfl_down(v, o, 64));
  return v;
}
DEVFN float blockSum256(float v, float* sm) {
  int lane = threadIdx.x & 63, w = threadIdx.x >> 6;
  v = waveSum(v);
  if (lane == 0) sm[w] = v;
  __syncthreads();
  if (threadIdx.x == 0) sm[4] = sm[0] + sm[1] + sm[2] + sm[3];
  __syncthreads();
  float t = sm[4];
  __syncthreads();
  return t;
}
DEVFN float blockSum384(float v, float* sm) {
  int lane = threadIdx.x & 63, w = threadIdx.x >> 6;  // 0..5
  v = waveSum(v);
  if (lane == 0) sm[w] = v;
  __syncthreads();
  if (threadIdx.x == 0) sm[6] = sm[0] + sm[1] + sm[2] + sm[3] + sm[4] + sm[5];
  __syncthreads();
  float t = sm[6];
  __syncthreads();
  return t;
}
// 512-thread (8-wave) block reduces; sm must have >= 9 slots
DEVFN float blockSum512(float v, float* sm) {
  int lane = threadIdx.x & 63, w = threadIdx.x >> 6;  // 0..7
  v = waveSum(v);
  if (lane == 0) sm[w] = v;
  __syncthreads();
  if (threadIdx.x == 0) {
    float a = sm[0];
#pragma unroll
    for (int i = 1; i < 8; i++) a += sm[i];
    sm[8] = a;
  }
  __syncthreads();
  float t = sm[8];
  __syncthreads();
  return t;
}
DEVFN float blockMax512(float v, float* sm) {
  int lane = threadIdx.x & 63, w = threadIdx.x >> 6;
  v = waveMax(v);
  if (lane == 0) sm[w] = v;
  __syncthreads();
  if (threadIdx.x == 0) {
    float a = sm[0];
#pragma unroll
    for (int i = 1; i < 8; i++) a = fmaxf(a, sm[i]);
    sm[8] = a;
  }
  __syncthreads();
  float t = sm[8];
  __syncthreads();
  return t;
}

// ---- K1: gather 6 entity slots (48 blocks: slot x batch-chunk), bn0 partial moments
__global__ __launch_bounds__(256) void k_gather48(
    const int* i1, const int* i2, const int* i3, const int* i4, const int* i5,
    const int* i6, const float* Ew, float* ws) {
  __shared__ float red[8];
  int blk = blockIdx.x, t = threadIdx.x;
  int s = blk >> 3, ch = blk & 7;
  const int* idx = (s == 0) ? i1 : (s == 1) ? i2 : (s == 2) ? i3
                 : (s == 3) ? i4 : (s == 4) ? i5 : i6;
  float sum = 0.f, sq = 0.f;
  for (int ii = t; ii < 64 * D; ii += 256) {
    int b = ch * 64 + ii / D, d = ii % D;
    float v = Ew[(long long)idx[b] * D + d];
    ws[OFF_X + b * IMN + s * D + d] = v;
    sum += v; sq += v * v;
  }
  float ts = blockSum256(sum, red);
  float tq = blockSum256(sq, red);
  if (t == 0) {
    ws[OFF_BN0P + (s * 8 + ch) * 2]     = ts;
    ws[OFF_BN0P + (s * 8 + ch) * 2 + 1] = tq;
  }
}

// ---- K2: gather relation rows (512 blocks, float4)
__global__ __launch_bounds__(256) void k_gather_r(const int* ridx, const float* Rw,
                                                  float* ws) {
  int b = blockIdx.x, t = threadIdx.x;
  const float4* src = (const float4*)(Rw + (long long)ridx[b] * REL);
  float4* dst = (float4*)(ws + OFF_R + b * REL);
  for (int c = t; c < REL / 4; c += 256) dst[c] = src[c];
}

// ---- K3: bn0 finalize + apply + e_mean (400 blocks cover B*D exactly)
__global__ __launch_bounds__(256) void k_bn0_apply(const float* g0, const float* b0, float* ws) {
  __shared__ float stats[12];
  int blk = blockIdx.x, t = threadIdx.x;
  if (t < 6) {
    float sum = 0.f, sq = 0.f;
#pragma unroll
    for (int ch = 0; ch < 8; ch++) {
      sum += ws[OFF_BN0P + (t * 8 + ch) * 2];
      sq  += ws[OFF_BN0P + (t * 8 + ch) * 2 + 1];
    }
    const float n = (float)(B * D);
    float m = sum / n;
    float var = sq / n - m * m;
    stats[2 * t] = m;
    stats[2 * t + 1] = rsqrtf(var + EPS);
  }
  __syncthreads();
  int i = blk * 256 + t;                  // i < B*D always (400*256 == B*D)
  int b = i / D, d = i - b * D;
  float g = g0[0], bb = b0[0];
  float acc = 0.f;
#pragma unroll
  for (int s = 0; s < 6; s++) {
    float v = ws[OFF_X + b * IMN + s * D + d];
    v = (v - stats[2 * s]) * stats[2 * s + 1] * g + bb;
    ws[OFF_X + b * IMN + s * D + d] = v;
    acc += v;
  }
  ws[OFF_EM + i] = acc * (1.f / 6.f);
}

// ---- K4: per-sample patch moments S[9], G[45] (Gram trick for BN1)
__global__ __launch_bounds__(256) void k_gram(float* ws) {
  __shared__ float img[IMN];
  int b = blockIdx.x, t = threadIdx.x;
  for (int i = t; i < IMN; i += 256) img[i] = ws[OFF_X + b * IMN + i];
  __syncthreads();
  float S[9]; float G[45];
#pragma unroll
  for (int a = 0; a < 9; a++) S[a] = 0.f;
#pragma unroll
  for (int u = 0; u < 45; u++) G[u] = 0.f;
  for (int p = t; p < NP; p += 256) {
    int oy = p / FW, ox = p - oy * FW;
    float tp[9];
#pragma unroll
    for (int kh = 0; kh < 3; kh++)
#pragma unroll
      for (int kw = 0; kw < 3; kw++)
        tp[kh * 3 + kw] = img[(oy + kh) * IMW + ox + kw];
    int u = 0;
#pragma unroll
    for (int a = 0; a < 9; a++) {
      S[a] += tp[a];
#pragma unroll
      for (int c = a; c < 9; c++) { G[u] += tp[a] * tp[c]; u++; }
    }
  }
#pragma unroll
  for (int a = 0; a < 9; a++) S[a] = waveSum(S[a]);
#pragma unroll
  for (int u = 0; u < 45; u++) G[u] = waveSum(G[u]);
  __shared__ float part[4][54];
  int lane = t & 63, w = t >> 6;
  if (lane == 0) {
#pragma unroll
    for (int a = 0; a < 9; a++) part[w][a] = S[a];
#pragma unroll
    for (int u = 0; u < 45; u++) part[w][9 + u] = G[u];
  }
  __syncthreads();
  if (t < 54) {
    float v = part[0][t] + part[1][t] + part[2][t] + part[3][t];
    if (t < 9) ws[OFF_S + b * 9 + t] = v;
    else       ws[OFF_G + b * 45 + (t - 9)] = v;
  }
}

// ---- K5: BN2 per-column stats (8 blocks, covers all 1800 columns)
__global__ __launch_bounds__(256) void k_bn2_stats(float* ws) {
  int c = blockIdx.x * 256 + threadIdx.x;
  if (c >= REL) return;
  const float* r = ws + OFF_R;
  float s = 0.f, q = 0.f;
  for (int b = 0; b < B; b++) { float v = r[b * REL + c]; s += v; q += v * v; }
  float m = s / (float)B;
  float var = q / (float)B - m * m;
  ws[OFF_BN2M + c] = m;
  ws[OFF_BN2S + c] = rsqrtf(var + EPS);
}

// ---- K6: q = e_mean @ Q (d-loop unrolled x8: 8 independent loads in flight)
__global__ __launch_bounds__(256) void k_q(const float* Qm, float* ws) {
  int i = blockIdx.x * 256 + threadIdx.x;
  if (i >= B * D) return;
  int b = i / D, col = i - b * D;
  const float* em = ws + OFF_EM + b * D;
  float a = 0.f;
  for (int d0 = 0; d0 < D; d0 += 8) {   // 25 bursts
    float qm[8], ev[8];
#pragma unroll
    for (int dd = 0; dd < 8; dd++) {
      qm[dd] = Qm[(d0 + dd) * D + col];
      ev[dd] = em[d0 + dd];
    }
#pragma unroll
    for (int dd = 0; dd < 8; dd++) a = fmaf(ev[dd], qm[dd], a);
  }
  ws[OFF_Q + i] = a;
}

// ---- K7: k/v GEMM, split-K over 5 REL-chunks x 128 row-groups = 640 blocks.
__global__ __launch_bounds__(256) void k_kv(const float* Km, const float* Vm, float* ws) {
  __shared__ float rs[KV_CLEN][KV_RB];   // 360 x 4 x 4B = 5.76 KB
  int blk = blockIdx.x, t = threadIdx.x;
  int g = blk / KV_CH, ch = blk % KV_CH;
  int c0 = ch * KV_CLEN;
  for (int ii = t; ii < KV_RB * KV_CLEN; ii += 256) {
    int c = ii >> 2, u = ii & 3;
    rs[c][u] = ws[OFF_R + (g * KV_RB + u) * REL + c0 + c];
  }
  __syncthreads();
  int i = t;
  if (i >= D) return;
  float ak[4] = {0.f, 0.f, 0.f, 0.f}, av[4] = {0.f, 0.f, 0.f, 0.f};
  for (int cb = 0; cb < KV_CLEN; cb += 8) {   // 45 bursts
    float km[8], vm[8];
#pragma unroll
    for (int cc = 0; cc < 8; cc++) {          // 16 independent loads in flight
      km[cc] = Km[(c0 + cb + cc) * D + i];
      vm[cc] = Vm[(c0 + cb + cc) * D + i];
    }
#pragma unroll
    for (int cc = 0; cc < 8; cc++) {
      float4 rv = *(const float4*)&rs[cb + cc][0];
      ak[0] = fmaf(rv.x, km[cc], ak[0]); av[0] = fmaf(rv.x, vm[cc], av[0]);
      ak[1] = fmaf(rv.y, km[cc], ak[1]); av[1] = fmaf(rv.y, vm[cc], av[1]);
      ak[2] = fmaf(rv.z, km[cc], ak[2]); av[2] = fmaf(rv.z, vm[cc], av[2]);
      ak[3] = fmaf(rv.w, km[cc], ak[3]); av[3] = fmaf(rv.w, vm[cc], av[3]);
    }
  }
  float* dk = (ch == 0) ? (ws + OFF_K) : (ws + OFF_PK + (ch - 1) * (B * D));
  float* dv = (ch == 0) ? (ws + OFF_V) : (ws + OFF_PV + (ch - 1) * (B * D));
#pragma unroll
  for (int u = 0; u < 4; u++) {
    dk[i * B + (g * 4 + u)] = ak[u];   // kT[d][b] layout in every buffer
    dv[(g * 4 + u) * D + i] = av[u];   // v[b][d]
  }
}

// ---- K7b: sum the 4 split-K partials into K/V (800 blocks, plain elementwise)
__global__ __launch_bounds__(256) void k_kvfix(float* ws) {
  int i = blockIdx.x * 256 + threadIdx.x;   // covers 2*B*D = 204800 exactly
  if (i < B * D) {
    float a = ws[OFF_K + i];
#pragma unroll
    for (int s = 0; s < 4; s++) a += ws[OFF_PK + s * (B * D) + i];
    ws[OFF_K + i] = a;
  } else {
    int j = i - B * D;
    float a = ws[OFF_V + j];
#pragma unroll
    for (int s = 0; s < 4; s++) a += ws[OFF_PV + s * (B * D) + j];
    ws[OFF_V + j] = a;
  }
}

// ---- K8: apply BN2 -> conv weights
__global__ __launch_bounds__(256) void k_bn2_apply(const float* g2, const float* b2, float* ws) {
  int i = blockIdx.x * 256 + threadIdx.x;
  if (i >= B * REL) return;
  int c = i % REL;
  float v = ws[OFF_R + i];
  ws[OFF_W + i] = (v - ws[OFF_BN2M + c]) * ws[OFF_BN2S + c] * g2[c] + b2[c];
}

// ---- K9: attention, 1 query/block, 512 threads (8 waves).
// Round-11 PMC: 256 blocks = 1 wave/SIMD, VALUBusy 9% -> pure latency stall.
// Now: 512 blocks x 8 waves = 4 waves/SIMD TLP; score phase has NO j-loop
// (one key per thread); d-loop unrolled x8; PV split across two 256-thread
// j-groups (chain halved) with LDS combine.
__global__ __launch_bounds__(512) void k_attn(float* ws) {
  __shared__ float qs[D];
  __shared__ float sc[B];
  __shared__ float part[2][D];
  __shared__ float red[9];
  int b = blockIdx.x, t = threadIdx.x;
  for (int i = t; i < D; i += 512) qs[i] = ws[OFF_Q + b * D + i];
  __syncthreads();
  // score: thread t owns key j=t
  const float* kT = ws + OFF_K;
  float a = 0.f;
  for (int d0 = 0; d0 < D; d0 += 8) {   // 25 bursts, 8 loads in flight
    float kv[8];
#pragma unroll
    for (int dd = 0; dd < 8; dd++) kv[dd] = kT[(d0 + dd) * B + t];
#pragma unroll
    for (int dd = 0; dd < 8; dd++) a = fmaf(qs[d0 + dd], kv[dd], a);
  }
  a *= INV_SQRT_D;
  float gmax = blockMax512(a, red);
  float e = __expf(a - gmax);
  sc[t] = e;
  float tot = blockSum512(e, red);   // internal syncs publish sc[]
  float inv = 1.f / tot;
  // PV: two 256-thread groups each cover half the keys
  int grp = t >> 8, dd = t & 255;
  if (dd < D) {
    const float* v = ws + OFF_V + (grp * 256) * D;
    const float* scl = &sc[grp * 256];
    float acc = 0.f;
    for (int j0 = 0; j0 < 256; j0 += 8) {   // 32 bursts
      float vv[8];
#pragma unroll
      for (int jj = 0; jj < 8; jj++) vv[jj] = v[(j0 + jj) * D + dd];
#pragma unroll
      for (int jj = 0; jj < 8; jj++) acc = fmaf(scl[j0 + jj], vv[jj], acc);
    }
    part[grp][dd] = acc;
  }
  __syncthreads();
  if (t < D) ws[OFF_ATT + b * D + t] = (part[0][t] + part[1][t]) * inv;
}

// ---- K10: BN1 per-channel stats from (w, S, G)
__global__ __launch_bounds__(256) void k_bn1_stats(float* ws) {
  __shared__ float red[8];
  int j = blockIdx.x, t = threadIdx.x;
  float s = 0.f, q = 0.f;
  for (int b = t; b < B; b += 256) {
    const float* w9 = ws + OFF_W + b * REL + j * 9;
    float wr[9];
#pragma unroll
    for (int k = 0; k < 9; k++) wr[k] = w9[k];
    const float* Sb = ws + OFF_S + b * 9;
    const float* Gb = ws + OFF_G + b * 45;
    float sl = 0.f;
#pragma unroll
    for (int k = 0; k < 9; k++) sl = fmaf(wr[k], Sb[k], sl);
    float ql = 0.f;
    int u = 0;
#pragma unroll
    for (int a = 0; a < 9; a++) {
      ql = fmaf(wr[a] * wr[a], Gb[u], ql); u++;
#pragma unroll
      for (int c = a + 1; c < 9; c++) { ql = fmaf(2.f * wr[a] * wr[c], Gb[u], ql); u++; }
    }
    s += sl; q += ql;
  }
  float ts = blockSum256(s, red);
  float tq = blockSum256(q, red);
  if (t == 0) {
    const float N = (float)B * (float)NP;
    float m = ts / N;
    float var = tq / N - m * m;
    ws[OFF_BN1M + j] = m;
    ws[OFF_BN1S + j] = rsqrtf(var + EPS);
  }
}

// ---- K11: wp = fc6_W^T @ p , bp = fc6_b . p
__global__ __launch_bounds__(256) void k_wp(const float* W, const float* bias,
                                            const float* pv, float* ws) {
  int p = blockIdx.x * 256 + threadIdx.x;
  if (p < NP) {
    float a = 0.f;
    for (int n = 0; n < 100; n++) a = fmaf(W[n * NP + p], pv[n], a);
    ws[OFF_WP + p] = a;
  } else if (p == NP) {
    float a = 0.f;
    for (int n = 0; n < 100; n++) a = fmaf(bias[n], pv[n], a);
    ws[OFF_BP] = a;
  }
}

// ---- K12: final fused conv + BN1 + relu + attention + spatial fc reduce (384 thr)
__global__ __launch_bounds__(384) void k_final(const float* g1, const float* b1,
                                               float* ws, float* out) {
  __shared__ float img[IMN];
  __shared__ float wpl[NP];
  __shared__ float packed[RNUM * 12];   // [w0..w8]*sc, bb, aj, pad
  __shared__ float red[8];
  int b = blockIdx.x, t = threadIdx.x;
  for (int i = t; i < IMN; i += 384) img[i] = ws[OFF_X + b * IMN + i];
  for (int i = t; i < NP; i += 384) wpl[i] = ws[OFF_WP + i];
  if (t < RNUM) {
    int j = t;
    float m = ws[OFF_BN1M + j], is = ws[OFF_BN1S + j];
    float sc = is * g1[j];
    float bb = b1[j] - m * sc;
    const float* w9 = ws + OFF_W + b * REL + j * 9;
#pragma unroll
    for (int k = 0; k < 9; k++) packed[j * 12 + k] = w9[k] * sc;
    packed[j * 12 + 9]  = bb;
    packed[j * 12 + 10] = ws[OFF_ATT + b * D + j];
    packed[j * 12 + 11] = 0.f;
  }
  __syncthreads();
  float taps[3][9];
  float wv[3];
#pragma unroll
  for (int pp = 0; pp < 3; pp++) {
    int p = t + pp * 384;
    bool ok = (p < NP);
    int pc = ok ? p : 0;
    int oy = pc / FW, ox = pc - oy * FW;
#pragma unroll
    for (int kh = 0; kh < 3; kh++)
#pragma unroll
      for (int kw = 0; kw < 3; kw++)
        taps[pp][kh * 3 + kw] = img[(oy + kh) * IMW + ox + kw];
    wv[pp] = ok ? wpl[p] : 0.f;
  }
  float acc = 0.f;
  for (int j = 0; j < RNUM; j++) {
    const float4* rec = (const float4*)&packed[j * 12];
    float4 r0 = rec[0], r1 = rec[1], r2 = rec[2];
    float zs = 0.f;
#pragma unroll
    for (int pp = 0; pp < 3; pp++) {
      float y = r2.y;  // bb
      y = fmaf(taps[pp][0], r0.x, y);
      y = fmaf(taps[pp][1], r0.y, y);
      y = fmaf(taps[pp][2], r0.z, y);
      y = fmaf(taps[pp][3], r0.w, y);
      y = fmaf(taps[pp][4], r1.x, y);
      y = fmaf(taps[pp][5], r1.y, y);
      y = fmaf(taps[pp][6], r1.z, y);
      y = fmaf(taps[pp][7], r1.w, y);
      y = fmaf(taps[pp][8], r2.x, y);
      float z = fmaxf(y, 0.f);
      zs = fmaf(z, wv[pp], zs);
    }
    acc = fmaf(zs, r2.z, acc);  // * aj
  }
  float tot = blockSum384(acc, red);
  if (t == 0) out[b] = tot + ws[OFF_BP];
}

extern "C" void kernel_launch(void* const* d_in, const int* in_sizes, int n_in,
                              void* d_out, int out_size, void* d_ws, size_t ws_size,
                              hipStream_t stream) {
  const int*   r_idx = (const int*)d_in[0];
  const int*   e1 = (const int*)d_in[1];
  const int*   e2 = (const int*)d_in[2];
  const int*   e3 = (const int*)d_in[3];
  const int*   e4 = (const int*)d_in[4];
  const int*   e5 = (const int*)d_in[5];
  const int*   e6 = (const int*)d_in[6];
  const float* E_w  = (const float*)d_in[7];
  const float* R_w  = (const float*)d_in[8];
  const float* bn0g = (const float*)d_in[9];
  const float* bn0b = (const float*)d_in[10];
  const float* bn1g = (const float*)d_in[11];
  const float* bn1b = (const float*)d_in[12];
  const float* bn2g = (const float*)d_in[13];
  const float* bn2b = (const float*)d_in[14];
  const float* Qm   = (const float*)d_in[15];
  const float* Km   = (const float*)d_in[16];
  const float* Vm   = (const float*)d_in[17];
  const float* fc6W = (const float*)d_in[18];
  const float* fc6b = (const float*)d_in[19];
  const float* pv   = (const float*)d_in[20];
  float* ws  = (float*)d_ws;
  float* out = (float*)d_out;

  k_gather48<<<48, 256, 0, stream>>>(e1, e2, e3, e4, e5, e6, E_w, ws);
  k_gather_r<<<512, 256, 0, stream>>>(r_idx, R_w, ws);
  k_bn0_apply<<<400, 256, 0, stream>>>(bn0g, bn0b, ws);
  k_gram<<<B, 256, 0, stream>>>(ws);
  k_bn2_stats<<<8, 256, 0, stream>>>(ws);
  k_q<<<400, 256, 0, stream>>>(Qm, ws);
  k_kv<<<128 * KV_CH, 256, 0, stream>>>(Km, Vm, ws);
  k_kvfix<<<800, 256, 0, stream>>>(ws);
  k_bn2_apply<<<3600, 256, 0, stream>>>(bn2g, bn2b, ws);
  k_attn<<<B, 512, 0, stream>>>(ws);
  k_bn1_stats<<<RNUM, 256, 0, stream>>>(ws);
  k_wp<<<6, 256, 0, stream>>>(fc6W, fc6b, pv, ws);
  k_final<<<B, 384, 0, stream>>>(bn1g, bn1b, ws, out);
}

// Round 13
// 299.471 us; speedup vs baseline: 1.4316x; 1.0361x over previous
//
#include <hip/hip_runtime.h>

#define DEVFN __device__ __forceinline__

namespace {
constexpr int B    = 512;
constexpr int D    = 200;
constexpr int RNUM = 200;
constexpr int REL  = 1800;
constexpr int FH   = 58, FW = 18, NP = FH * FW;     // 1044
constexpr int IMH  = 60, IMW = 20, IMN = IMH * IMW; // 1200
constexpr float EPS = 1e-5f;
constexpr float INV_SQRT_D = 0.07071067811865475f;  // 1/sqrt(200)

// k_kv split-K: 4 rows x 5 REL-chunks, 640 blocks (2.5 waves/SIMD of TLP)
constexpr int KV_RB   = 4;
constexpr int KV_CH   = 5;
constexpr int KV_CLEN = REL / KV_CH;   // 360 = 8*45

// k_final split: 2 halves of 100 channels each
constexpr int FJ = RNUM / 2;           // 100

// workspace layout (float offsets)
constexpr int OFF_X    = 0;                      // B*IMN  conv image (bn0'd)
constexpr int OFF_EM   = OFF_X   + B * IMN;      // B*D
constexpr int OFF_R    = OFF_EM  + B * D;        // B*REL
constexpr int OFF_W    = OFF_R   + B * REL;      // B*REL  bn2(r)
constexpr int OFF_Q    = OFF_W   + B * REL;      // B*D
constexpr int OFF_K    = OFF_Q   + B * D;        // B*D    K TRANSPOSED: kT[d][b]
constexpr int OFF_V    = OFF_K   + B * D;        // B*D    V normal: v[b][d]
constexpr int OFF_ATT  = OFF_V   + B * D;        // B*D
constexpr int OFF_S    = OFF_ATT + B * D;        // B*9
constexpr int OFF_G    = OFF_S   + B * 9;        // B*45
constexpr int OFF_BN0P = OFF_G   + B * 45;       // 96 = 6 slots * 8 chunks * {sum,sq}
constexpr int OFF_BN2M = OFF_BN0P + 96;          // REL
constexpr int OFF_BN2S = OFF_BN2M + REL;         // REL
constexpr int OFF_BN1M = OFF_BN2S + REL;         // RNUM
constexpr int OFF_BN1S = OFF_BN1M + RNUM;        // RNUM
constexpr int OFF_WP   = OFF_BN1S + RNUM;        // NP
constexpr int OFF_BP   = OFF_WP  + NP;           // 1
constexpr int OFF_PK   = ((OFF_BP + 1 + 3) / 4) * 4;  // 4 x B*D partial K (chunks 1-4)
constexpr int OFF_PV   = OFF_PK + 4 * B * D;           // 4 x B*D partial V
constexpr int OFF_FP   = OFF_PV + 4 * B * D;           // B*2 k_final partials
// total = OFF_FP + 2*B  = ~3.82M floats = ~15.3 MB
} // namespace

DEVFN float waveSum(float v) {
#pragma unroll
  for (int o = 32; o; o >>= 1) v += __shfl_down(v, o, 64);
  return v;
}
DEVFN float waveMax(float v) {
#pragma unroll
  for (int o = 32; o; o >>= 1) v = fmaxf(v, __shfl_down(v, o, 64));
  return v;
}
DEVFN float blockSum256(float v, float* sm) {
  int lane = threadIdx.x & 63, w = threadIdx.x >> 6;
  v = waveSum(v);
  if (lane == 0) sm[w] = v;
  __syncthreads();
  if (threadIdx.x == 0) sm[4] = sm[0] + sm[1] + sm[2] + sm[3];
  __syncthreads();
  float t = sm[4];
  __syncthreads();
  return t;
}
DEVFN float blockSum384(float v, float* sm) {
  int lane = threadIdx.x & 63, w = threadIdx.x >> 6;  // 0..5
  v = waveSum(v);
  if (lane == 0) sm[w] = v;
  __syncthreads();
  if (threadIdx.x == 0) sm[6] = sm[0] + sm[1] + sm[2] + sm[3] + sm[4] + sm[5];
  __syncthreads();
  float t = sm[6];
  __syncthreads();
  return t;
}
// 512-thread (8-wave) block reduces; sm must have >= 9 slots
DEVFN float blockSum512(float v, float* sm) {
  int lane = threadIdx.x & 63, w = threadIdx.x >> 6;  // 0..7
  v = waveSum(v);
  if (lane == 0) sm[w] = v;
  __syncthreads();
  if (threadIdx.x == 0) {
    float a = sm[0];
#pragma unroll
    for (int i = 1; i < 8; i++) a += sm[i];
    sm[8] = a;
  }
  __syncthreads();
  float t = sm[8];
  __syncthreads();
  return t;
}
DEVFN float blockMax512(float v, float* sm) {
  int lane = threadIdx.x & 63, w = threadIdx.x >> 6;
  v = waveMax(v);
  if (lane == 0) sm[w] = v;
  __syncthreads();
  if (threadIdx.x == 0) {
    float a = sm[0];
#pragma unroll
    for (int i = 1; i < 8; i++) a = fmaxf(a, sm[i]);
    sm[8] = a;
  }
  __syncthreads();
  float t = sm[8];
  __syncthreads();
  return t;
}

// ---- K1: gather 6 entity slots (48 blocks: slot x batch-chunk), bn0 partial moments
__global__ __launch_bounds__(256) void k_gather48(
    const int* i1, const int* i2, const int* i3, const int* i4, const int* i5,
    const int* i6, const float* Ew, float* ws) {
  __shared__ float red[8];
  int blk = blockIdx.x, t = threadIdx.x;
  int s = blk >> 3, ch = blk & 7;
  const int* idx = (s == 0) ? i1 : (s == 1) ? i2 : (s == 2) ? i3
                 : (s == 3) ? i4 : (s == 4) ? i5 : i6;
  float sum = 0.f, sq = 0.f;
  for (int ii = t; ii < 64 * D; ii += 256) {
    int b = ch * 64 + ii / D, d = ii % D;
    float v = Ew[(long long)idx[b] * D + d];
    ws[OFF_X + b * IMN + s * D + d] = v;
    sum += v; sq += v * v;
  }
  float ts = blockSum256(sum, red);
  float tq = blockSum256(sq, red);
  if (t == 0) {
    ws[OFF_BN0P + (s * 8 + ch) * 2]     = ts;
    ws[OFF_BN0P + (s * 8 + ch) * 2 + 1] = tq;
  }
}

// ---- K2: gather relation rows (512 blocks, float4)
__global__ __launch_bounds__(256) void k_gather_r(const int* ridx, const float* Rw,
                                                  float* ws) {
  int b = blockIdx.x, t = threadIdx.x;
  const float4* src = (const float4*)(Rw + (long long)ridx[b] * REL);
  float4* dst = (float4*)(ws + OFF_R + b * REL);
  for (int c = t; c < REL / 4; c += 256) dst[c] = src[c];
}

// ---- K3: bn0 finalize + apply + e_mean (400 blocks cover B*D exactly)
__global__ __launch_bounds__(256) void k_bn0_apply(const float* g0, const float* b0, float* ws) {
  __shared__ float stats[12];
  int blk = blockIdx.x, t = threadIdx.x;
  if (t < 6) {
    float sum = 0.f, sq = 0.f;
#pragma unroll
    for (int ch = 0; ch < 8; ch++) {
      sum += ws[OFF_BN0P + (t * 8 + ch) * 2];
      sq  += ws[OFF_BN0P + (t * 8 + ch) * 2 + 1];
    }
    const float n = (float)(B * D);
    float m = sum / n;
    float var = sq / n - m * m;
    stats[2 * t] = m;
    stats[2 * t + 1] = rsqrtf(var + EPS);
  }
  __syncthreads();
  int i = blk * 256 + t;                  // i < B*D always (400*256 == B*D)
  int b = i / D, d = i - b * D;
  float g = g0[0], bb = b0[0];
  float acc = 0.f;
#pragma unroll
  for (int s = 0; s < 6; s++) {
    float v = ws[OFF_X + b * IMN + s * D + d];
    v = (v - stats[2 * s]) * stats[2 * s + 1] * g + bb;
    ws[OFF_X + b * IMN + s * D + d] = v;
    acc += v;
  }
  ws[OFF_EM + i] = acc * (1.f / 6.f);
}

// ---- K4: per-sample patch moments S[9], G[45] (Gram trick for BN1)
__global__ __launch_bounds__(256) void k_gram(float* ws) {
  __shared__ float img[IMN];
  int b = blockIdx.x, t = threadIdx.x;
  for (int i = t; i < IMN; i += 256) img[i] = ws[OFF_X + b * IMN + i];
  __syncthreads();
  float S[9]; float G[45];
#pragma unroll
  for (int a = 0; a < 9; a++) S[a] = 0.f;
#pragma unroll
  for (int u = 0; u < 45; u++) G[u] = 0.f;
  for (int p = t; p < NP; p += 256) {
    int oy = p / FW, ox = p - oy * FW;
    float tp[9];
#pragma unroll
    for (int kh = 0; kh < 3; kh++)
#pragma unroll
      for (int kw = 0; kw < 3; kw++)
        tp[kh * 3 + kw] = img[(oy + kh) * IMW + ox + kw];
    int u = 0;
#pragma unroll
    for (int a = 0; a < 9; a++) {
      S[a] += tp[a];
#pragma unroll
      for (int c = a; c < 9; c++) { G[u] += tp[a] * tp[c]; u++; }
    }
  }
#pragma unroll
  for (int a = 0; a < 9; a++) S[a] = waveSum(S[a]);
#pragma unroll
  for (int u = 0; u < 45; u++) G[u] = waveSum(G[u]);
  __shared__ float part[4][54];
  int lane = t & 63, w = t >> 6;
  if (lane == 0) {
#pragma unroll
    for (int a = 0; a < 9; a++) part[w][a] = S[a];
#pragma unroll
    for (int u = 0; u < 45; u++) part[w][9 + u] = G[u];
  }
  __syncthreads();
  if (t < 54) {
    float v = part[0][t] + part[1][t] + part[2][t] + part[3][t];
    if (t < 9) ws[OFF_S + b * 9 + t] = v;
    else       ws[OFF_G + b * 45 + (t - 9)] = v;
  }
}

// ---- K5: BN2 per-column stats (8 blocks, covers all 1800 columns)
__global__ __launch_bounds__(256) void k_bn2_stats(float* ws) {
  int c = blockIdx.x * 256 + threadIdx.x;
  if (c >= REL) return;
  const float* r = ws + OFF_R;
  float s = 0.f, q = 0.f;
  for (int b = 0; b < B; b++) { float v = r[b * REL + c]; s += v; q += v * v; }
  float m = s / (float)B;
  float var = q / (float)B - m * m;
  ws[OFF_BN2M + c] = m;
  ws[OFF_BN2S + c] = rsqrtf(var + EPS);
}

// ---- K6: q = e_mean @ Q (d-loop unrolled x8: 8 independent loads in flight)
__global__ __launch_bounds__(256) void k_q(const float* Qm, float* ws) {
  int i = blockIdx.x * 256 + threadIdx.x;
  if (i >= B * D) return;
  int b = i / D, col = i - b * D;
  const float* em = ws + OFF_EM + b * D;
  float a = 0.f;
  for (int d0 = 0; d0 < D; d0 += 8) {   // 25 bursts
    float qm[8], ev[8];
#pragma unroll
    for (int dd = 0; dd < 8; dd++) {
      qm[dd] = Qm[(d0 + dd) * D + col];
      ev[dd] = em[d0 + dd];
    }
#pragma unroll
    for (int dd = 0; dd < 8; dd++) a = fmaf(ev[dd], qm[dd], a);
  }
  ws[OFF_Q + i] = a;
}

// ---- K7: k/v GEMM, split-K over 5 REL-chunks x 128 row-groups = 640 blocks.
__global__ __launch_bounds__(256) void k_kv(const float* Km, const float* Vm, float* ws) {
  __shared__ float rs[KV_CLEN][KV_RB];   // 360 x 4 x 4B = 5.76 KB
  int blk = blockIdx.x, t = threadIdx.x;
  int g = blk / KV_CH, ch = blk % KV_CH;
  int c0 = ch * KV_CLEN;
  for (int ii = t; ii < KV_RB * KV_CLEN; ii += 256) {
    int c = ii >> 2, u = ii & 3;
    rs[c][u] = ws[OFF_R + (g * KV_RB + u) * REL + c0 + c];
  }
  __syncthreads();
  int i = t;
  if (i >= D) return;
  float ak[4] = {0.f, 0.f, 0.f, 0.f}, av[4] = {0.f, 0.f, 0.f, 0.f};
  for (int cb = 0; cb < KV_CLEN; cb += 8) {   // 45 bursts
    float km[8], vm[8];
#pragma unroll
    for (int cc = 0; cc < 8; cc++) {          // 16 independent loads in flight
      km[cc] = Km[(c0 + cb + cc) * D + i];
      vm[cc] = Vm[(c0 + cb + cc) * D + i];
    }
#pragma unroll
    for (int cc = 0; cc < 8; cc++) {
      float4 rv = *(const float4*)&rs[cb + cc][0];
      ak[0] = fmaf(rv.x, km[cc], ak[0]); av[0] = fmaf(rv.x, vm[cc], av[0]);
      ak[1] = fmaf(rv.y, km[cc], ak[1]); av[1] = fmaf(rv.y, vm[cc], av[1]);
      ak[2] = fmaf(rv.z, km[cc], ak[2]); av[2] = fmaf(rv.z, vm[cc], av[2]);
      ak[3] = fmaf(rv.w, km[cc], ak[3]); av[3] = fmaf(rv.w, vm[cc], av[3]);
    }
  }
  float* dk = (ch == 0) ? (ws + OFF_K) : (ws + OFF_PK + (ch - 1) * (B * D));
  float* dv = (ch == 0) ? (ws + OFF_V) : (ws + OFF_PV + (ch - 1) * (B * D));
#pragma unroll
  for (int u = 0; u < 4; u++) {
    dk[i * B + (g * 4 + u)] = ak[u];   // kT[d][b] layout in every buffer
    dv[(g * 4 + u) * D + i] = av[u];   // v[b][d]
  }
}

// ---- K7b: sum the 4 split-K partials into K/V (800 blocks, plain elementwise)
__global__ __launch_bounds__(256) void k_kvfix(float* ws) {
  int i = blockIdx.x * 256 + threadIdx.x;   // covers 2*B*D = 204800 exactly
  if (i < B * D) {
    float a = ws[OFF_K + i];
#pragma unroll
    for (int s = 0; s < 4; s++) a += ws[OFF_PK + s * (B * D) + i];
    ws[OFF_K + i] = a;
  } else {
    int j = i - B * D;
    float a = ws[OFF_V + j];
#pragma unroll
    for (int s = 0; s < 4; s++) a += ws[OFF_PV + s * (B * D) + j];
    ws[OFF_V + j] = a;
  }
}

// ---- K8: apply BN2 -> conv weights
__global__ __launch_bounds__(256) void k_bn2_apply(const float* g2, const float* b2, float* ws) {
  int i = blockIdx.x * 256 + threadIdx.x;
  if (i >= B * REL) return;
  int c = i % REL;
  float v = ws[OFF_R + i];
  ws[OFF_W + i] = (v - ws[OFF_BN2M + c]) * ws[OFF_BN2S + c] * g2[c] + b2[c];
}

// ---- K9: attention, 1 query/block, 512 threads (8 waves)
__global__ __launch_bounds__(512) void k_attn(float* ws) {
  __shared__ float qs[D];
  __shared__ float sc[B];
  __shared__ float part[2][D];
  __shared__ float red[9];
  int b = blockIdx.x, t = threadIdx.x;
  for (int i = t; i < D; i += 512) qs[i] = ws[OFF_Q + b * D + i];
  __syncthreads();
  // score: thread t owns key j=t
  const float* kT = ws + OFF_K;
  float a = 0.f;
  for (int d0 = 0; d0 < D; d0 += 8) {   // 25 bursts, 8 loads in flight
    float kv[8];
#pragma unroll
    for (int dd = 0; dd < 8; dd++) kv[dd] = kT[(d0 + dd) * B + t];
#pragma unroll
    for (int dd = 0; dd < 8; dd++) a = fmaf(qs[d0 + dd], kv[dd], a);
  }
  a *= INV_SQRT_D;
  float gmax = blockMax512(a, red);
  float e = __expf(a - gmax);
  sc[t] = e;
  float tot = blockSum512(e, red);   // internal syncs publish sc[]
  float inv = 1.f / tot;
  // PV: two 256-thread groups each cover half the keys
  int grp = t >> 8, dd = t & 255;
  if (dd < D) {
    const float* v = ws + OFF_V + (grp * 256) * D;
    const float* scl = &sc[grp * 256];
    float acc = 0.f;
    for (int j0 = 0; j0 < 256; j0 += 8) {   // 32 bursts
      float vv[8];
#pragma unroll
      for (int jj = 0; jj < 8; jj++) vv[jj] = v[(j0 + jj) * D + dd];
#pragma unroll
      for (int jj = 0; jj < 8; jj++) acc = fmaf(scl[j0 + jj], vv[jj], acc);
    }
    part[grp][dd] = acc;
  }
  __syncthreads();
  if (t < D) ws[OFF_ATT + b * D + t] = (part[0][t] + part[1][t]) * inv;
}

// ---- K10: BN1 per-channel stats from (w, S, G)
__global__ __launch_bounds__(256) void k_bn1_stats(float* ws) {
  __shared__ float red[8];
  int j = blockIdx.x, t = threadIdx.x;
  float s = 0.f, q = 0.f;
  for (int b = t; b < B; b += 256) {
    const float* w9 = ws + OFF_W + b * REL + j * 9;
    float wr[9];
#pragma unroll
    for (int k = 0; k < 9; k++) wr[k] = w9[k];
    const float* Sb = ws + OFF_S + b * 9;
    const float* Gb = ws + OFF_G + b * 45;
    float sl = 0.f;
#pragma unroll
    for (int k = 0; k < 9; k++) sl = fmaf(wr[k], Sb[k], sl);
    float ql = 0.f;
    int u = 0;
#pragma unroll
    for (int a = 0; a < 9; a++) {
      ql = fmaf(wr[a] * wr[a], Gb[u], ql); u++;
#pragma unroll
      for (int c = a + 1; c < 9; c++) { ql = fmaf(2.f * wr[a] * wr[c], Gb[u], ql); u++; }
    }
    s += sl; q += ql;
  }
  float ts = blockSum256(s, red);
  float tq = blockSum256(q, red);
  if (t == 0) {
    const float N = (float)B * (float)NP;
    float m = ts / N;
    float var = tq / N - m * m;
    ws[OFF_BN1M + j] = m;
    ws[OFF_BN1S + j] = rsqrtf(var + EPS);
  }
}

// ---- K11: wp = fc6_W^T @ p , bp = fc6_b . p
__global__ __launch_bounds__(256) void k_wp(const float* W, const float* bias,
                                            const float* pv, float* ws) {
  int p = blockIdx.x * 256 + threadIdx.x;
  if (p < NP) {
    float a = 0.f;
    for (int n = 0; n < 100; n++) a = fmaf(W[n * NP + p], pv[n], a);
    ws[OFF_WP + p] = a;
  } else if (p == NP) {
    float a = 0.f;
    for (int n = 0; n < 100; n++) a = fmaf(bias[n], pv[n], a);
    ws[OFF_BP] = a;
  }
}

// ---- K12: final fused conv+BN1+relu+att+fc. Round-12 PMC: 512 blocks = 2/CU
// grid-limited (Occ 22%), VALUBusy 70%. Split channel loop: 1024 blocks x 100
// channels -> 4+ blocks/CU residency; partials combined in k_out.
__global__ __launch_bounds__(384) void k_final(const float* g1, const float* b1,
                                               float* ws) {
  __shared__ float img[IMN];
  __shared__ float wpl[NP];
  __shared__ float packed[FJ * 12];     // [w0..w8]*sc, bb, aj, pad (100 ch)
  __shared__ float red[8];
  int blk = blockIdx.x, t = threadIdx.x;
  int b = blk >> 1, half = blk & 1;
  int j0 = half * FJ;
  for (int i = t; i < IMN; i += 384) img[i] = ws[OFF_X + b * IMN + i];
  for (int i = t; i < NP; i += 384) wpl[i] = ws[OFF_WP + i];
  if (t < FJ) {
    int j = j0 + t;
    float m = ws[OFF_BN1M + j], is = ws[OFF_BN1S + j];
    float sc = is * g1[j];
    float bb = b1[j] - m * sc;
    const float* w9 = ws + OFF_W + b * REL + j * 9;
#pragma unroll
    for (int k = 0; k < 9; k++) packed[t * 12 + k] = w9[k] * sc;
    packed[t * 12 + 9]  = bb;
    packed[t * 12 + 10] = ws[OFF_ATT + b * D + j];
    packed[t * 12 + 11] = 0.f;
  }
  __syncthreads();
  float taps[3][9];
  float wv[3];
#pragma unroll
  for (int pp = 0; pp < 3; pp++) {
    int p = t + pp * 384;
    bool ok = (p < NP);
    int pc = ok ? p : 0;
    int oy = pc / FW, ox = pc - oy * FW;
#pragma unroll
    for (int kh = 0; kh < 3; kh++)
#pragma unroll
      for (int kw = 0; kw < 3; kw++)
        taps[pp][kh * 3 + kw] = img[(oy + kh) * IMW + ox + kw];
    wv[pp] = ok ? wpl[p] : 0.f;
  }
  float acc = 0.f;
  for (int jj = 0; jj < FJ; jj++) {
    const float4* rec = (const float4*)&packed[jj * 12];
    float4 r0 = rec[0], r1 = rec[1], r2 = rec[2];
    float zs = 0.f;
#pragma unroll
    for (int pp = 0; pp < 3; pp++) {
      float y = r2.y;  // bb
      y = fmaf(taps[pp][0], r0.x, y);
      y = fmaf(taps[pp][1], r0.y, y);
      y = fmaf(taps[pp][2], r0.z, y);
      y = fmaf(taps[pp][3], r0.w, y);
      y = fmaf(taps[pp][4], r1.x, y);
      y = fmaf(taps[pp][5], r1.y, y);
      y = fmaf(taps[pp][6], r1.z, y);
      y = fmaf(taps[pp][7], r1.w, y);
      y = fmaf(taps[pp][8], r2.x, y);
      float z = fmaxf(y, 0.f);
      zs = fmaf(z, wv[pp], zs);
    }
    acc = fmaf(zs, r2.z, acc);  // * aj
  }
  float tot = blockSum384(acc, red);
  if (t == 0) ws[OFF_FP + b * 2 + half] = tot;
}

// ---- K13: combine k_final partials + bp -> out (2 blocks)
__global__ __launch_bounds__(256) void k_out(float* ws, float* out) {
  int b = blockIdx.x * 256 + threadIdx.x;
  if (b < B) out[b] = ws[OFF_FP + 2 * b] + ws[OFF_FP + 2 * b + 1] + ws[OFF_BP];
}

extern "C" void kernel_launch(void* const* d_in, const int* in_sizes, int n_in,
                              void* d_out, int out_size, void* d_ws, size_t ws_size,
                              hipStream_t stream) {
  const int*   r_idx = (const int*)d_in[0];
  const int*   e1 = (const int*)d_in[1];
  const int*   e2 = (const int*)d_in[2];
  const int*   e3 = (const int*)d_in[3];
  const int*   e4 = (const int*)d_in[4];
  const int*   e5 = (const int*)d_in[5];
  const int*   e6 = (const int*)d_in[6];
  const float* E_w  = (const float*)d_in[7];
  const float* R_w  = (const float*)d_in[8];
  const float* bn0g = (const float*)d_in[9];
  const float* bn0b = (const float*)d_in[10];
  const float* bn1g = (const float*)d_in[11];
  const float* bn1b = (const float*)d_in[12];
  const float* bn2g = (const float*)d_in[13];
  const float* bn2b = (const float*)d_in[14];
  const float* Qm   = (const float*)d_in[15];
  const float* Km   = (const float*)d_in[16];
  const float* Vm   = (const float*)d_in[17];
  const float* fc6W = (const float*)d_in[18];
  const float* fc6b = (const float*)d_in[19];
  const float* pv   = (const float*)d_in[20];
  float* ws  = (float*)d_ws;
  float* out = (float*)d_out;

  k_gather48<<<48, 256, 0, stream>>>(e1, e2, e3, e4, e5, e6, E_w, ws);
  k_gather_r<<<512, 256, 0, stream>>>(r_idx, R_w, ws);
  k_bn0_apply<<<400, 256, 0, stream>>>(bn0g, bn0b, ws);
  k_gram<<<B, 256, 0, stream>>>(ws);
  k_bn2_stats<<<8, 256, 0, stream>>>(ws);
  k_q<<<400, 256, 0, stream>>>(Qm, ws);
  k_kv<<<128 * KV_CH, 256, 0, stream>>>(Km, Vm, ws);
  k_kvfix<<<800, 256, 0, stream>>>(ws);
  k_bn2_apply<<<3600, 256, 0, stream>>>(bn2g, bn2b, ws);
  k_attn<<<B, 512, 0, stream>>>(ws);
  k_bn1_stats<<<RNUM, 256, 0, stream>>>(ws);
  k_wp<<<6, 256, 0, stream>>>(fc6W, fc6b, pv, ws);
  k_final<<<2 * B, 384, 0, stream>>>(bn1g, bn1b, ws);
  k_out<<<2, 256, 0, stream>>>(ws, out);
}

// Round 14
// 269.841 us; speedup vs baseline: 1.5888x; 1.1098x over previous
//
#include <hip/hip_runtime.h>

#define DEVFN __device__ __forceinline__

namespace {
constexpr int B    = 512;
constexpr int D    = 200;
constexpr int RNUM = 200;
constexpr int REL  = 1800;
constexpr int FH   = 58, FW = 18, NP = FH * FW;     // 1044
constexpr int IMH  = 60, IMW = 20, IMN = IMH * IMW; // 1200
constexpr float EPS = 1e-5f;
constexpr float INV_SQRT_D = 0.07071067811865475f;  // 1/sqrt(200)

// k_kv split-K: 4 rows x 5 REL-chunks, 640 blocks (2.5 waves/SIMD of TLP)
constexpr int KV_RB   = 4;
constexpr int KV_CH   = 5;
constexpr int KV_CLEN = REL / KV_CH;   // 360 = 8*45

// k_final split: 2 halves of 100 channels each
constexpr int FJ = RNUM / 2;           // 100

// bn0 gather: 16 batch-chunks of 32
constexpr int G_CH = 16;

// workspace layout (float offsets)
constexpr int OFF_X    = 0;                      // B*IMN  conv image (bn0'd)
constexpr int OFF_EM   = OFF_X   + B * IMN;      // B*D
constexpr int OFF_R    = OFF_EM  + B * D;        // B*REL
constexpr int OFF_W    = OFF_R   + B * REL;      // B*REL  bn2(r)
constexpr int OFF_Q    = OFF_W   + B * REL;      // B*D
constexpr int OFF_K    = OFF_Q   + B * D;        // B*D    K TRANSPOSED: kT[d][b]
constexpr int OFF_V    = OFF_K   + B * D;        // B*D    V normal: v[b][d]
constexpr int OFF_ATT  = OFF_V   + B * D;        // B*D
constexpr int OFF_S    = OFF_ATT + B * D;        // B*9
constexpr int OFF_G    = OFF_S   + B * 9;        // B*45
constexpr int OFF_BN0P = OFF_G   + B * 45;       // 192 = 6 slots * 16 chunks * {sum,sq}
constexpr int OFF_BN2M = OFF_BN0P + 192;         // REL
constexpr int OFF_BN2S = OFF_BN2M + REL;         // REL
constexpr int OFF_BN1M = OFF_BN2S + REL;         // RNUM
constexpr int OFF_BN1S = OFF_BN1M + RNUM;        // RNUM
constexpr int OFF_WP   = OFF_BN1S + RNUM;        // NP
constexpr int OFF_BP   = OFF_WP  + NP;           // 1
constexpr int OFF_PK   = ((OFF_BP + 1 + 3) / 4) * 4;  // 4 x B*D partial K (chunks 1-4)
constexpr int OFF_PV   = OFF_PK + 4 * B * D;           // 4 x B*D partial V
constexpr int OFF_FP   = OFF_PV + 4 * B * D;           // B*2 k_final partials
constexpr int OFF_B2P  = OFF_FP + 2 * B;               // 16*REL bn2 partials (8 sum + 8 sq)
// total = OFF_B2P + 16*REL ~ 3.85M floats ~ 15.4 MB
} // namespace

DEVFN float waveSum(float v) {
#pragma unroll
  for (int o = 32; o; o >>= 1) v += __shfl_down(v, o, 64);
  return v;
}
DEVFN float waveMax(float v) {
#pragma unroll
  for (int o = 32; o; o >>= 1) v = fmaxf(v, __shfl_down(v, o, 64));
  return v;
}
DEVFN float blockSum256(float v, float* sm) {
  int lane = threadIdx.x & 63, w = threadIdx.x >> 6;
  v = waveSum(v);
  if (lane == 0) sm[w] = v;
  __syncthreads();
  if (threadIdx.x == 0) sm[4] = sm[0] + sm[1] + sm[2] + sm[3];
  __syncthreads();
  float t = sm[4];
  __syncthreads();
  return t;
}
DEVFN float blockSum384(float v, float* sm) {
  int lane = threadIdx.x & 63, w = threadIdx.x >> 6;  // 0..5
  v = waveSum(v);
  if (lane == 0) sm[w] = v;
  __syncthreads();
  if (threadIdx.x == 0) sm[6] = sm[0] + sm[1] + sm[2] + sm[3] + sm[4] + sm[5];
  __syncthreads();
  float t = sm[6];
  __syncthreads();
  return t;
}
// 512-thread (8-wave) block reduces; sm must have >= 9 slots
DEVFN float blockSum512(float v, float* sm) {
  int lane = threadIdx.x & 63, w = threadIdx.x >> 6;  // 0..7
  v = waveSum(v);
  if (lane == 0) sm[w] = v;
  __syncthreads();
  if (threadIdx.x == 0) {
    float a = sm[0];
#pragma unroll
    for (int i = 1; i < 8; i++) a += sm[i];
    sm[8] = a;
  }
  __syncthreads();
  float t = sm[8];
  __syncthreads();
  return t;
}
DEVFN float blockMax512(float v, float* sm) {
  int lane = threadIdx.x & 63, w = threadIdx.x >> 6;
  v = waveMax(v);
  if (lane == 0) sm[w] = v;
  __syncthreads();
  if (threadIdx.x == 0) {
    float a = sm[0];
#pragma unroll
    for (int i = 1; i < 8; i++) a = fmaxf(a, sm[i]);
    sm[8] = a;
  }
  __syncthreads();
  float t = sm[8];
  __syncthreads();
  return t;
}

// ---- K1: gather 6 entity slots (96 blocks: slot x 16 batch-chunks of 32), bn0 partials
__global__ __launch_bounds__(256) void k_gather96(
    const int* i1, const int* i2, const int* i3, const int* i4, const int* i5,
    const int* i6, const float* Ew, float* ws) {
  __shared__ float red[8];
  int blk = blockIdx.x, t = threadIdx.x;
  int s = blk >> 4, ch = blk & 15;
  const int* idx = (s == 0) ? i1 : (s == 1) ? i2 : (s == 2) ? i3
                 : (s == 3) ? i4 : (s == 4) ? i5 : i6;
  float sum = 0.f, sq = 0.f;
  for (int ii = t; ii < 32 * D; ii += 256) {   // 25 iters
    int b = ch * 32 + ii / D, d = ii % D;
    float v = Ew[(long long)idx[b] * D + d];
    ws[OFF_X + b * IMN + s * D + d] = v;
    sum += v; sq += v * v;
  }
  float ts = blockSum256(sum, red);
  float tq = blockSum256(sq, red);
  if (t == 0) {
    ws[OFF_BN0P + (s * G_CH + ch) * 2]     = ts;
    ws[OFF_BN0P + (s * G_CH + ch) * 2 + 1] = tq;
  }
}

// ---- K2: gather relation rows (512 blocks, float4)
__global__ __launch_bounds__(256) void k_gather_r(const int* ridx, const float* Rw,
                                                  float* ws) {
  int b = blockIdx.x, t = threadIdx.x;
  const float4* src = (const float4*)(Rw + (long long)ridx[b] * REL);
  float4* dst = (float4*)(ws + OFF_R + b * REL);
  for (int c = t; c < REL / 4; c += 256) dst[c] = src[c];
}

// ---- K3: bn0 finalize + apply + e_mean (400 blocks cover B*D exactly)
__global__ __launch_bounds__(256) void k_bn0_apply(const float* g0, const float* b0, float* ws) {
  __shared__ float stats[12];
  int blk = blockIdx.x, t = threadIdx.x;
  if (t < 6) {
    float sum = 0.f, sq = 0.f;
#pragma unroll
    for (int ch = 0; ch < G_CH; ch++) {
      sum += ws[OFF_BN0P + (t * G_CH + ch) * 2];
      sq  += ws[OFF_BN0P + (t * G_CH + ch) * 2 + 1];
    }
    const float n = (float)(B * D);
    float m = sum / n;
    float var = sq / n - m * m;
    stats[2 * t] = m;
    stats[2 * t + 1] = rsqrtf(var + EPS);
  }
  __syncthreads();
  int i = blk * 256 + t;                  // i < B*D always (400*256 == B*D)
  int b = i / D, d = i - b * D;
  float g = g0[0], bb = b0[0];
  float acc = 0.f;
#pragma unroll
  for (int s = 0; s < 6; s++) {
    float v = ws[OFF_X + b * IMN + s * D + d];
    v = (v - stats[2 * s]) * stats[2 * s + 1] * g + bb;
    ws[OFF_X + b * IMN + s * D + d] = v;
    acc += v;
  }
  ws[OFF_EM + i] = acc * (1.f / 6.f);
}

// ---- K4: per-sample patch moments S[9], G[45] (Gram trick for BN1)
__global__ __launch_bounds__(256) void k_gram(float* ws) {
  __shared__ float img[IMN];
  int b = blockIdx.x, t = threadIdx.x;
  for (int i = t; i < IMN; i += 256) img[i] = ws[OFF_X + b * IMN + i];
  __syncthreads();
  float S[9]; float G[45];
#pragma unroll
  for (int a = 0; a < 9; a++) S[a] = 0.f;
#pragma unroll
  for (int u = 0; u < 45; u++) G[u] = 0.f;
  for (int p = t; p < NP; p += 256) {
    int oy = p / FW, ox = p - oy * FW;
    float tp[9];
#pragma unroll
    for (int kh = 0; kh < 3; kh++)
#pragma unroll
      for (int kw = 0; kw < 3; kw++)
        tp[kh * 3 + kw] = img[(oy + kh) * IMW + ox + kw];
    int u = 0;
#pragma unroll
    for (int a = 0; a < 9; a++) {
      S[a] += tp[a];
#pragma unroll
      for (int c = a; c < 9; c++) { G[u] += tp[a] * tp[c]; u++; }
    }
  }
#pragma unroll
  for (int a = 0; a < 9; a++) S[a] = waveSum(S[a]);
#pragma unroll
  for (int u = 0; u < 45; u++) G[u] = waveSum(G[u]);
  __shared__ float part[4][54];
  int lane = t & 63, w = t >> 6;
  if (lane == 0) {
#pragma unroll
    for (int a = 0; a < 9; a++) part[w][a] = S[a];
#pragma unroll
    for (int u = 0; u < 45; u++) part[w][9 + u] = G[u];
  }
  __syncthreads();
  if (t < 54) {
    float v = part[0][t] + part[1][t] + part[2][t] + part[3][t];
    if (t < 9) ws[OFF_S + b * 9 + t] = v;
    else       ws[OFF_G + b * 45 + (t - 9)] = v;
  }
}

// ---- K5a: BN2 partial stats. Round-13 triage: 8 blocks x 512-iter serial chain
// was the worst remaining latency case. Now 64 blocks (8 col-groups x 8
// row-chunks of 64), inner x8 unroll -> 8 loads in flight, 8x TLP.
__global__ __launch_bounds__(256) void k_bn2_part(float* ws) {
  int blk = blockIdx.x, t = threadIdx.x;
  int rc = blk >> 3, cb = blk & 7;
  int c = cb * 256 + t;
  if (c >= REL) return;
  const float* r = ws + OFF_R + (rc * 64) * REL;
  float s = 0.f, q = 0.f;
  for (int b0 = 0; b0 < 64; b0 += 8) {
    float v[8];
#pragma unroll
    for (int j = 0; j < 8; j++) v[j] = r[(b0 + j) * REL + c];
#pragma unroll
    for (int j = 0; j < 8; j++) { s += v[j]; q = fmaf(v[j], v[j], q); }
  }
  ws[OFF_B2P + rc * REL + c]           = s;
  ws[OFF_B2P + 8 * REL + rc * REL + c] = q;
}

// ---- K5b: combine bn2 partials (8 blocks)
__global__ __launch_bounds__(256) void k_bn2_fin(float* ws) {
  int c = blockIdx.x * 256 + threadIdx.x;
  if (c >= REL) return;
  float s = 0.f, q = 0.f;
#pragma unroll
  for (int rc = 0; rc < 8; rc++) {
    s += ws[OFF_B2P + rc * REL + c];
    q += ws[OFF_B2P + 8 * REL + rc * REL + c];
  }
  float m = s / (float)B;
  float var = q / (float)B - m * m;
  ws[OFF_BN2M + c] = m;
  ws[OFF_BN2S + c] = rsqrtf(var + EPS);
}

// ---- K6: q = e_mean @ Q (d-loop unrolled x8: 8 independent loads in flight)
__global__ __launch_bounds__(256) void k_q(const float* Qm, float* ws) {
  int i = blockIdx.x * 256 + threadIdx.x;
  if (i >= B * D) return;
  int b = i / D, col = i - b * D;
  const float* em = ws + OFF_EM + b * D;
  float a = 0.f;
  for (int d0 = 0; d0 < D; d0 += 8) {   // 25 bursts
    float qm[8], ev[8];
#pragma unroll
    for (int dd = 0; dd < 8; dd++) {
      qm[dd] = Qm[(d0 + dd) * D + col];
      ev[dd] = em[d0 + dd];
    }
#pragma unroll
    for (int dd = 0; dd < 8; dd++) a = fmaf(ev[dd], qm[dd], a);
  }
  ws[OFF_Q + i] = a;
}

// ---- K7: k/v GEMM, split-K over 5 REL-chunks x 128 row-groups = 640 blocks.
__global__ __launch_bounds__(256) void k_kv(const float* Km, const float* Vm, float* ws) {
  __shared__ float rs[KV_CLEN][KV_RB];   // 360 x 4 x 4B = 5.76 KB
  int blk = blockIdx.x, t = threadIdx.x;
  int g = blk / KV_CH, ch = blk % KV_CH;
  int c0 = ch * KV_CLEN;
  for (int ii = t; ii < KV_RB * KV_CLEN; ii += 256) {
    int c = ii >> 2, u = ii & 3;
    rs[c][u] = ws[OFF_R + (g * KV_RB + u) * REL + c0 + c];
  }
  __syncthreads();
  int i = t;
  if (i >= D) return;
  float ak[4] = {0.f, 0.f, 0.f, 0.f}, av[4] = {0.f, 0.f, 0.f, 0.f};
  for (int cb = 0; cb < KV_CLEN; cb += 8) {   // 45 bursts
    float km[8], vm[8];
#pragma unroll
    for (int cc = 0; cc < 8; cc++) {          // 16 independent loads in flight
      km[cc] = Km[(c0 + cb + cc) * D + i];
      vm[cc] = Vm[(c0 + cb + cc) * D + i];
    }
#pragma unroll
    for (int cc = 0; cc < 8; cc++) {
      float4 rv = *(const float4*)&rs[cb + cc][0];
      ak[0] = fmaf(rv.x, km[cc], ak[0]); av[0] = fmaf(rv.x, vm[cc], av[0]);
      ak[1] = fmaf(rv.y, km[cc], ak[1]); av[1] = fmaf(rv.y, vm[cc], av[1]);
      ak[2] = fmaf(rv.z, km[cc], ak[2]); av[2] = fmaf(rv.z, vm[cc], av[2]);
      ak[3] = fmaf(rv.w, km[cc], ak[3]); av[3] = fmaf(rv.w, vm[cc], av[3]);
    }
  }
  float* dk = (ch == 0) ? (ws + OFF_K) : (ws + OFF_PK + (ch - 1) * (B * D));
  float* dv = (ch == 0) ? (ws + OFF_V) : (ws + OFF_PV + (ch - 1) * (B * D));
#pragma unroll
  for (int u = 0; u < 4; u++) {
    dk[i * B + (g * 4 + u)] = ak[u];   // kT[d][b] layout in every buffer
    dv[(g * 4 + u) * D + i] = av[u];   // v[b][d]
  }
}

// ---- K7b: sum the 4 split-K partials into K/V (800 blocks, plain elementwise)
__global__ __launch_bounds__(256) void k_kvfix(float* ws) {
  int i = blockIdx.x * 256 + threadIdx.x;   // covers 2*B*D = 204800 exactly
  if (i < B * D) {
    float a = ws[OFF_K + i];
#pragma unroll
    for (int s = 0; s < 4; s++) a += ws[OFF_PK + s * (B * D) + i];
    ws[OFF_K + i] = a;
  } else {
    int j = i - B * D;
    float a = ws[OFF_V + j];
#pragma unroll
    for (int s = 0; s < 4; s++) a += ws[OFF_PV + s * (B * D) + j];
    ws[OFF_V + j] = a;
  }
}

// ---- K8: apply BN2 -> conv weights
__global__ __launch_bounds__(256) void k_bn2_apply(const float* g2, const float* b2, float* ws) {
  int i = blockIdx.x * 256 + threadIdx.x;
  if (i >= B * REL) return;
  int c = i % REL;
  float v = ws[OFF_R + i];
  ws[OFF_W + i] = (v - ws[OFF_BN2M + c]) * ws[OFF_BN2S + c] * g2[c] + b2[c];
}

// ---- K9: attention, 1 query/block, 512 threads (8 waves)
__global__ __launch_bounds__(512) void k_attn(float* ws) {
  __shared__ float qs[D];
  __shared__ float sc[B];
  __shared__ float part[2][D];
  __shared__ float red[9];
  int b = blockIdx.x, t = threadIdx.x;
  for (int i = t; i < D; i += 512) qs[i] = ws[OFF_Q + b * D + i];
  __syncthreads();
  // score: thread t owns key j=t
  const float* kT = ws + OFF_K;
  float a = 0.f;
  for (int d0 = 0; d0 < D; d0 += 8) {   // 25 bursts, 8 loads in flight
    float kv[8];
#pragma unroll
    for (int dd = 0; dd < 8; dd++) kv[dd] = kT[(d0 + dd) * B + t];
#pragma unroll
    for (int dd = 0; dd < 8; dd++) a = fmaf(qs[d0 + dd], kv[dd], a);
  }
  a *= INV_SQRT_D;
  float gmax = blockMax512(a, red);
  float e = __expf(a - gmax);
  sc[t] = e;
  float tot = blockSum512(e, red);   // internal syncs publish sc[]
  float inv = 1.f / tot;
  // PV: two 256-thread groups each cover half the keys
  int grp = t >> 8, dd = t & 255;
  if (dd < D) {
    const float* v = ws + OFF_V + (grp * 256) * D;
    const float* scl = &sc[grp * 256];
    float acc = 0.f;
    for (int j0 = 0; j0 < 256; j0 += 8) {   // 32 bursts
      float vv[8];
#pragma unroll
      for (int jj = 0; jj < 8; jj++) vv[jj] = v[(j0 + jj) * D + dd];
#pragma unroll
      for (int jj = 0; jj < 8; jj++) acc = fmaf(scl[j0 + jj], vv[jj], acc);
    }
    part[grp][dd] = acc;
  }
  __syncthreads();
  if (t < D) ws[OFF_ATT + b * D + t] = (part[0][t] + part[1][t]) * inv;
}

// ---- K10: BN1 per-channel stats from (w, S, G)
__global__ __launch_bounds__(256) void k_bn1_stats(float* ws) {
  __shared__ float red[8];
  int j = blockIdx.x, t = threadIdx.x;
  float s = 0.f, q = 0.f;
  for (int b = t; b < B; b += 256) {
    const float* w9 = ws + OFF_W + b * REL + j * 9;
    float wr[9];
#pragma unroll
    for (int k = 0; k < 9; k++) wr[k] = w9[k];
    const float* Sb = ws + OFF_S + b * 9;
    const float* Gb = ws + OFF_G + b * 45;
    float sl = 0.f;
#pragma unroll
    for (int k = 0; k < 9; k++) sl = fmaf(wr[k], Sb[k], sl);
    float ql = 0.f;
    int u = 0;
#pragma unroll
    for (int a = 0; a < 9; a++) {
      ql = fmaf(wr[a] * wr[a], Gb[u], ql); u++;
#pragma unroll
      for (int c = a + 1; c < 9; c++) { ql = fmaf(2.f * wr[a] * wr[c], Gb[u], ql); u++; }
    }
    s += sl; q += ql;
  }
  float ts = blockSum256(s, red);
  float tq = blockSum256(q, red);
  if (t == 0) {
    const float N = (float)B * (float)NP;
    float m = ts / N;
    float var = tq / N - m * m;
    ws[OFF_BN1M + j] = m;
    ws[OFF_BN1S + j] = rsqrtf(var + EPS);
  }
}

// ---- K11: wp = fc6_W^T @ p , bp = fc6_b . p (n-loop unrolled x4)
__global__ __launch_bounds__(256) void k_wp(const float* W, const float* bias,
                                            const float* pv, float* ws) {
  int p = blockIdx.x * 256 + threadIdx.x;
  if (p < NP) {
    float a = 0.f;
    for (int n0 = 0; n0 < 100; n0 += 4) {
      float wv[4], pvv[4];
#pragma unroll
      for (int j = 0; j < 4; j++) {
        wv[j]  = W[(n0 + j) * NP + p];
        pvv[j] = pv[n0 + j];
      }
#pragma unroll
      for (int j = 0; j < 4; j++) a = fmaf(wv[j], pvv[j], a);
    }
    ws[OFF_WP + p] = a;
  } else if (p == NP) {
    float a = 0.f;
    for (int n = 0; n < 100; n++) a = fmaf(bias[n], pv[n], a);
    ws[OFF_BP] = a;
  }
}

// ---- K12: final fused conv+BN1+relu+att+fc (1024 blocks x 100 channels)
__global__ __launch_bounds__(384) void k_final(const float* g1, const float* b1,
                                               float* ws) {
  __shared__ float img[IMN];
  __shared__ float wpl[NP];
  __shared__ float packed[FJ * 12];     // [w0..w8]*sc, bb, aj, pad (100 ch)
  __shared__ float red[8];
  int blk = blockIdx.x, t = threadIdx.x;
  int b = blk >> 1, half = blk & 1;
  int j0 = half * FJ;
  for (int i = t; i < IMN; i += 384) img[i] = ws[OFF_X + b * IMN + i];
  for (int i = t; i < NP; i += 384) wpl[i] = ws[OFF_WP + i];
  if (t < FJ) {
    int j = j0 + t;
    float m = ws[OFF_BN1M + j], is = ws[OFF_BN1S + j];
    float sc = is * g1[j];
    float bb = b1[j] - m * sc;
    const float* w9 = ws + OFF_W + b * REL + j * 9;
#pragma unroll
    for (int k = 0; k < 9; k++) packed[t * 12 + k] = w9[k] * sc;
    packed[t * 12 + 9]  = bb;
    packed[t * 12 + 10] = ws[OFF_ATT + b * D + j];
    packed[t * 12 + 11] = 0.f;
  }
  __syncthreads();
  float taps[3][9];
  float wv[3];
#pragma unroll
  for (int pp = 0; pp < 3; pp++) {
    int p = t + pp * 384;
    bool ok = (p < NP);
    int pc = ok ? p : 0;
    int oy = pc / FW, ox = pc - oy * FW;
#pragma unroll
    for (int kh = 0; kh < 3; kh++)
#pragma unroll
      for (int kw = 0; kw < 3; kw++)
        taps[pp][kh * 3 + kw] = img[(oy + kh) * IMW + ox + kw];
    wv[pp] = ok ? wpl[p] : 0.f;
  }
  float acc = 0.f;
  for (int jj = 0; jj < FJ; jj++) {
    const float4* rec = (const float4*)&packed[jj * 12];
    float4 r0 = rec[0], r1 = rec[1], r2 = rec[2];
    float zs = 0.f;
#pragma unroll
    for (int pp = 0; pp < 3; pp++) {
      float y = r2.y;  // bb
      y = fmaf(taps[pp][0], r0.x, y);
      y = fmaf(taps[pp][1], r0.y, y);
      y = fmaf(taps[pp][2], r0.z, y);
      y = fmaf(taps[pp][3], r0.w, y);
      y = fmaf(taps[pp][4], r1.x, y);
      y = fmaf(taps[pp][5], r1.y, y);
      y = fmaf(taps[pp][6], r1.z, y);
      y = fmaf(taps[pp][7], r1.w, y);
      y = fmaf(taps[pp][8], r2.x, y);
      float z = fmaxf(y, 0.f);
      zs = fmaf(z, wv[pp], zs);
    }
    acc = fmaf(zs, r2.z, acc);  // * aj
  }
  float tot = blockSum384(acc, red);
  if (t == 0) ws[OFF_FP + b * 2 + half] = tot;
}

// ---- K13: combine k_final partials + bp -> out (2 blocks)
__global__ __launch_bounds__(256) void k_out(float* ws, float* out) {
  int b = blockIdx.x * 256 + threadIdx.x;
  if (b < B) out[b] = ws[OFF_FP + 2 * b] + ws[OFF_FP + 2 * b + 1] + ws[OFF_BP];
}

extern "C" void kernel_launch(void* const* d_in, const int* in_sizes, int n_in,
                              void* d_out, int out_size, void* d_ws, size_t ws_size,
                              hipStream_t stream) {
  const int*   r_idx = (const int*)d_in[0];
  const int*   e1 = (const int*)d_in[1];
  const int*   e2 = (const int*)d_in[2];
  const int*   e3 = (const int*)d_in[3];
  const int*   e4 = (const int*)d_in[4];
  const int*   e5 = (const int*)d_in[5];
  const int*   e6 = (const int*)d_in[6];
  const float* E_w  = (const float*)d_in[7];
  const float* R_w  = (const float*)d_in[8];
  const float* bn0g = (const float*)d_in[9];
  const float* bn0b = (const float*)d_in[10];
  const float* bn1g = (const float*)d_in[11];
  const float* bn1b = (const float*)d_in[12];
  const float* bn2g = (const float*)d_in[13];
  const float* bn2b = (const float*)d_in[14];
  const float* Qm   = (const float*)d_in[15];
  const float* Km   = (const float*)d_in[16];
  const float* Vm   = (const float*)d_in[17];
  const float* fc6W = (const float*)d_in[18];
  const float* fc6b = (const float*)d_in[19];
  const float* pv   = (const float*)d_in[20];
  float* ws  = (float*)d_ws;
  float* out = (float*)d_out;

  k_gather96<<<96, 256, 0, stream>>>(e1, e2, e3, e4, e5, e6, E_w, ws);
  k_gather_r<<<512, 256, 0, stream>>>(r_idx, R_w, ws);
  k_bn0_apply<<<400, 256, 0, stream>>>(bn0g, bn0b, ws);
  k_gram<<<B, 256, 0, stream>>>(ws);
  k_bn2_part<<<64, 256, 0, stream>>>(ws);
  k_bn2_fin<<<8, 256, 0, stream>>>(ws);
  k_q<<<400, 256, 0, stream>>>(Qm, ws);
  k_kv<<<128 * KV_CH, 256, 0, stream>>>(Km, Vm, ws);
  k_kvfix<<<800, 256, 0, stream>>>(ws);
  k_bn2_apply<<<3600, 256, 0, stream>>>(bn2g, bn2b, ws);
  k_attn<<<B, 512, 0, stream>>>(ws);
  k_bn1_stats<<<RNUM, 256, 0, stream>>>(ws);
  k_wp<<<6, 256, 0, stream>>>(fc6W, fc6b, pv, ws);
  k_final<<<2 * B, 384, 0, stream>>>(bn1g, bn1b, ws);
  k_out<<<2, 256, 0, stream>>>(ws, out);
}